// Round 16
// baseline (869.793 us; speedup 1.0000x reference)
//
#include <hip/hip_runtime.h>

// EdgeConvBlock: B=32, N=1024, D=3, CIN=64, K=16, COUT=128x3
// Round 16: gemm7 — 512-thread blocks, 8 waves = 4 row-groups x 2 col-halves over
// the same 256x128 tile. Same ~49KB LDS per block -> 3 blocks/CU but 24 waves/CU
// (2x concurrency vs r15's 12). Per-rg __syncthreads (compute->store) keeps
// in-place y update race-free across col-half waves.

#define BB 32
#define NN 1024
#define CINC 64
#define KK 16
#define CO 128
#define NROW (BB*NN*KK)   // 524288
#define NROWSC (BB*NN)    // 32768

// ---- ws layout (bytes) ----
static const size_t OFF_FT   = 0;            // featsT f32 [B][N][64]       8,388,608
static const size_t OFF_IDX  = 8388608;      // idx int  [B][N][16]         2,097,152
static const size_t OFF_Y    = 10485760;     // y  bf16  [NROW][128]      134,217,728
static const size_t OFF_SC   = 144703488;    // sc f32   [NROWSC][128]     16,777,216
static const size_t OFF_PART = 161480704;    // partials f32 [2048][256] (2MB used of 8MB)
static const size_t OFF_WB   = 165675008;    // swizzled bf16 W [3][16384]     98,304
static const size_t OFF_S1   = 169869312;    // stage1 f32 [64][256]           65,536
static const size_t OFF_SB   = 169934848;    // scale/bias f32 [4][256]         4,096
static const size_t WS_NEED  = 169938944;

typedef __bf16 bf16x8v __attribute__((ext_vector_type(8)));
typedef float  f32x4v  __attribute__((ext_vector_type(4)));

__device__ __forceinline__ float bl(unsigned u){ return __uint_as_float(u<<16); }
__device__ __forceinline__ float bh(unsigned u){ return __uint_as_float(u & 0xffff0000u); }
__device__ __forceinline__ unsigned short bfr(float x){
  unsigned u = __float_as_uint(x);
  u += 0x7fffu + ((u>>16)&1u);
  return (unsigned short)(u>>16);
}
__device__ __forceinline__ unsigned short b16(float x){
  return __builtin_bit_cast(unsigned short, (__bf16)x);   // HW RNE convert
}

// ---------------- diagnostic sentinel ----------------
__global__ __launch_bounds__(256) void sentinel_kernel(float* __restrict__ out, int n, float v){
  int i = blockIdx.x*256 + threadIdx.x;
  if (i < n) out[i] = v;
}

// ---------------- transpose features (b,c,n) -> (b,n,c) ----------------
__global__ __launch_bounds__(256) void transpose_feats(const float* __restrict__ f,
                                                       float* __restrict__ ft){
  __shared__ __align__(16) float tile[64][65];
  int t = threadIdx.x;
  int b = blockIdx.x, n0 = blockIdx.y*64;
  for (int it=0; it<16; ++it){
    int flat = it*256 + t;
    int c = flat>>6, nl = flat&63;
    tile[c][nl] = f[(b*64 + c)*1024 + n0 + nl];
  }
  __syncthreads();
  for (int it=0; it<16; ++it){
    int flat = it*256 + t;
    int nl = flat>>6, c = flat&63;
    ft[((b<<10) + n0 + nl)*64 + c] = tile[c][nl];
  }
}

// ---------------- weight pre-swizzle: W[o][c] f32 -> bf16 frag order ----------------
// WB[lay][ (kb*8+cf)*64 + l ][j] = W[cf*16 + (l&15)][kb*32 + (l>>4)*8 + j]
__global__ __launch_bounds__(256) void convert_w(const float* __restrict__ W0,
                                                 const float* __restrict__ W1,
                                                 const float* __restrict__ W2,
                                                 unsigned short* __restrict__ WB){
  int tid = blockIdx.x*256 + threadIdx.x;      // 0..6143
  int lay = tid >> 11, rem = tid & 2047;
  int f = rem >> 6, l = rem & 63;
  int kb = f >> 3, cf = f & 7;
  int li = l & 15, lg = l >> 4;
  const float* Ws = lay==0 ? W0 : (lay==1 ? W1 : W2);
  int o = cf*16 + li;
  unsigned short p[8];
  #pragma unroll
  for (int j=0;j<8;++j) p[j] = bfr(Ws[o*128 + kb*32 + lg*8 + j]);
  uint4 o4;
  o4.x = (unsigned)p[0] | ((unsigned)p[1]<<16);
  o4.y = (unsigned)p[2] | ((unsigned)p[3]<<16);
  o4.z = (unsigned)p[4] | ((unsigned)p[5]<<16);
  o4.w = (unsigned)p[6] | ((unsigned)p[7]<<16);
  *reinterpret_cast<uint4*>(WB + (size_t)lay*16384 + (size_t)rem*8) = o4;
}

// ---------------- KNN v4: packed-key cascade, 32 queries x 8 chunks of 128 ----------------
// key = positive normal double: [bit62=1][fkey32(pd)][tie=1023-m] -> f64 order == top_k order.
__global__ __launch_bounds__(256) void knn_kernel(const float* __restrict__ pts,
                                                  int* __restrict__ idxout){
  __shared__ __align__(16) char smem[34816];
  float4* p4 = (float4*)smem;                          // [1024] during scan
  unsigned long long (*mk)[32][17] =
      (unsigned long long(*)[32][17])smem;             // [8][32][17] keys after scan

  int t = threadIdx.x;
  int b = blockIdx.x, g = blockIdx.y;
  for (int i=t; i<1024; i+=256){
    float a = pts[(b*3+0)*1024+i];
    float c = pts[(b*3+1)*1024+i];
    float d = pts[(b*3+2)*1024+i];
    float xx = __fadd_rn(__fadd_rn(__fmul_rn(a,a), __fmul_rn(c,c)), __fmul_rn(d,d));
    p4[i] = make_float4(a, c, d, xx);
  }
  __syncthreads();

  int q = t & 31, c = t >> 5;       // query-in-block, chunk
  int n = g*32 + q;
  float4 qp = p4[n];
  float qx=qp.x, qy=qp.y, qz=qp.z, qxx=qp.w;
  double vals[16];
  #pragma unroll
  for (int j=0;j<16;++j) vals[j] = 0.0;

  int m0 = c*128;
  for (int i0=0; i0<128; i0+=4){
    float4 cand[4];
    #pragma unroll
    for (int u=0;u<4;++u) cand[u] = p4[m0 + i0 + u];
    #pragma unroll
    for (int u=0;u<4;++u){
      int m = m0 + i0 + u;
      float inner = __fadd_rn(__fadd_rn(__fmul_rn(qx,cand[u].x), __fmul_rn(qy,cand[u].y)), __fmul_rn(qz,cand[u].z));
      float pd = __fsub_rn(__fsub_rn(__fmul_rn(2.0f, inner), qxx), cand[u].w);
      unsigned uv = __float_as_uint(pd);
      unsigned fk = uv ^ (0x80000000u | (unsigned)((int)uv >> 31));  // monotone f32->u32
      unsigned lo = (fk << 20) | (unsigned)(1023 - m);
      unsigned hi = 0x40000000u | (fk >> 12);
      hi = (m == n) ? 0u : hi;                                       // self -> tiny key
      double key = __builtin_bit_cast(double, ((unsigned long long)hi << 32) | lo);
      #pragma unroll
      for (int j=0;j<16;++j){
        double mx = fmax(vals[j], key);
        key = fmin(vals[j], key);
        vals[j] = mx;
      }
    }
  }
  __syncthreads();                    // scans done; points dead -> key lists live
  #pragma unroll
  for (int j=0;j<16;++j) mk[c][q][j] = __builtin_bit_cast(unsigned long long, vals[j]);
  mk[c][q][16] = 0ull;                // sentinel
  __syncthreads();

  if (t < 32){
    int qq = t;
    int p0=0,p1=0,p2=0,p3=0,p4i=0,p5=0,p6=0,p7=0;
    unsigned long long v0=mk[0][qq][0], v1=mk[1][qq][0], v2=mk[2][qq][0], v3=mk[3][qq][0];
    unsigned long long v4=mk[4][qq][0], v5=mk[5][qq][0], v6=mk[6][qq][0], v7=mk[7][qq][0];
    int* dst = idxout + ((size_t)((b<<10) + g*32 + qq))*16;
    #pragma unroll
    for (int j=0;j<16;++j){
      unsigned long long best = v0; int bc = 0;
      if (v1 > best){ best = v1; bc = 1; }
      if (v2 > best){ best = v2; bc = 2; }
      if (v3 > best){ best = v3; bc = 3; }
      if (v4 > best){ best = v4; bc = 4; }
      if (v5 > best){ best = v5; bc = 5; }
      if (v6 > best){ best = v6; bc = 6; }
      if (v7 > best){ best = v7; bc = 7; }
      dst[j] = 1023 - (int)(best & 1023ull);
      if      (bc==0){ ++p0; v0 = mk[0][qq][p0]; }
      else if (bc==1){ ++p1; v1 = mk[1][qq][p1]; }
      else if (bc==2){ ++p2; v2 = mk[2][qq][p2]; }
      else if (bc==3){ ++p3; v3 = mk[3][qq][p3]; }
      else if (bc==4){ ++p4i; v4 = mk[4][qq][p4i]; }
      else if (bc==5){ ++p5; v5 = mk[5][qq][p5]; }
      else if (bc==6){ ++p6; v6 = mk[6][qq][p6]; }
      else           { ++p7; v7 = mk[7][qq][p7]; }
    }
  }
}

// ---------------- GEMM v7: 512 threads, 8 waves = 4 row-groups x 2 col-halves ----------------
// MODE 0: x = (center || nbr-center); MODE 1: x = relu(yin*s+b), in-place safe via
// per-rg __syncthreads between compute (reads rg's rows) and store (writes rg's rows).
template<int MODE>
__global__ __launch_bounds__(512, 6) void gemm7(const float* __restrict__ featsT,
                                                const int* __restrict__ knnidx,
                                                const unsigned short* yin,
                                                const float* __restrict__ sb,
                                                const unsigned short* __restrict__ Wswz,
                                                unsigned short* yout,
                                                float* __restrict__ partials){
  __shared__ __align__(16) unsigned short Wl[16384];      // 32KB swizzled W (both halves)
  __shared__ __align__(16) unsigned short tb[8][16][68];  // 17KB per-wave transpose (64 cols)
  float* red = (float*)&tb[0][0][0];                      // 4KB alias (after final barrier)

  int t = threadIdx.x;
  int w = t >> 6, l = t & 63;
  int rw = w & 3, ch2 = w >> 2;       // row-group wave, col-half
  int li = l & 15, lg = l >> 4;

  // stage swizzled W: linear 32KB copy (512 threads x 4 iters x 16B)
  #pragma unroll
  for (int it=0; it<4; ++it){
    int v = it*512 + t;
    *reinterpret_cast<uint4*>(&Wl[v*8]) =
      *reinterpret_cast<const uint4*>(Wswz + (size_t)v*8);
  }
  __syncthreads();

  float ss[4] = {0.f,0.f,0.f,0.f};
  float sq[4] = {0.f,0.f,0.f,0.f};

  // -------- epilogue helper: stats + LDS scatter (no sync inside) --------
  auto scatter = [&](f32x4v (&acc)[4]){
    #pragma unroll
    for (int cf=0; cf<4; ++cf){
      ss[cf] += acc[cf][0]+acc[cf][1]+acc[cf][2]+acc[cf][3];
      sq[cf] += acc[cf][0]*acc[cf][0]+acc[cf][1]*acc[cf][1]+acc[cf][2]*acc[cf][2]+acc[cf][3]*acc[cf][3];
    }
    #pragma unroll
    for (int cf=0; cf<4; ++cf){
      tb[w][lg*4 + 0][cf*16 + li] = b16(acc[cf][0]);
      tb[w][lg*4 + 1][cf*16 + li] = b16(acc[cf][1]);
      tb[w][lg*4 + 2][cf*16 + li] = b16(acc[cf][2]);
      tb[w][lg*4 + 3][cf*16 + li] = b16(acc[cf][3]);
    }
  };
  // -------- coalesced store of one rg tile (after barrier) --------
  auto store_tile = [&](int rg){
    size_t rbase = (size_t)blockIdx.x*256 + rw*64 + rg*16;
    int r8 = l >> 3, ch = l & 7;      // 8 rows x 8 chunks per instruction
    #pragma unroll
    for (int s2=0; s2<2; ++s2){
      int r2 = s2*8 + r8;
      const unsigned short* src = &tb[w][r2][ch*8];
      unsigned short* dst = yout + (rbase + r2)*128 + ch2*64 + ch*8;
      *reinterpret_cast<uint4*>(dst) = *reinterpret_cast<const uint4*>(src);
    }
  };

  if constexpr (MODE == 1){
    const unsigned short* ybase = yin + ((size_t)blockIdx.x*256 + rw*64 + li)*128 + lg*8;
    uint4 yb[2][4];
    #pragma unroll
    for (int kb=0; kb<4; ++kb)
      yb[0][kb] = *reinterpret_cast<const uint4*>(ybase + kb*32);
    #pragma unroll
    for (int rg=0; rg<4; ++rg){
      if (rg < 3){   // 1-ahead prefetch (rows of rg+1; written only in rg+1's store phase)
        #pragma unroll
        for (int kb=0; kb<4; ++kb)
          yb[(rg+1)&1][kb] = *reinterpret_cast<const uint4*>(ybase + (size_t)(rg+1)*2048 + kb*32);
      }
      f32x4v acc[4] = {};
      #pragma unroll
      for (int kb=0; kb<4; ++kb){
        int c0 = kb*32 + lg*8;
        uint4 yv = yb[rg&1][kb];
        float4 s0 = *reinterpret_cast<const float4*>(sb + c0);
        float4 s1 = *reinterpret_cast<const float4*>(sb + c0 + 4);
        float4 b0 = *reinterpret_cast<const float4*>(sb + 128 + c0);
        float4 b1 = *reinterpret_cast<const float4*>(sb + 128 + c0 + 4);
        bf16x8v av;
        av[0] = (__bf16)fmaxf(fmaf(bl(yv.x), s0.x, b0.x), 0.f);
        av[1] = (__bf16)fmaxf(fmaf(bh(yv.x), s0.y, b0.y), 0.f);
        av[2] = (__bf16)fmaxf(fmaf(bl(yv.y), s0.z, b0.z), 0.f);
        av[3] = (__bf16)fmaxf(fmaf(bh(yv.y), s0.w, b0.w), 0.f);
        av[4] = (__bf16)fmaxf(fmaf(bl(yv.z), s1.x, b1.x), 0.f);
        av[5] = (__bf16)fmaxf(fmaf(bh(yv.z), s1.y, b1.y), 0.f);
        av[6] = (__bf16)fmaxf(fmaf(bl(yv.w), s1.z, b1.z), 0.f);
        av[7] = (__bf16)fmaxf(fmaf(bh(yv.w), s1.w, b1.w), 0.f);
        #pragma unroll
        for (int cf=0; cf<4; ++cf){
          uint4 b4 = *reinterpret_cast<const uint4*>(&Wl[((kb*8 + ch2*4 + cf)*64 + l)*8]);
          acc[cf] = __builtin_amdgcn_mfma_f32_16x16x32_bf16(av, __builtin_bit_cast(bf16x8v, b4), acc[cf], 0, 0, 0);
        }
      }
      scatter(acc);
      __syncthreads();       // all reads of rg's rows done (block-wide) before writes
      store_tile(rg);
    }
  } else {
    int b = blockIdx.x >> 6;                     // 64 blocks per batch
    int nbase = (blockIdx.x & 63)*16 + rw*4;     // point n for rg = nbase + rg
    const float* fb = featsT + (((size_t)b)<<10)*64;
    int nbr[4];
    #pragma unroll
    for (int rg=0; rg<4; ++rg)
      nbr[rg] = knnidx[((size_t)((b<<10) + nbase + rg))*16 + li];
    float4 cg[2][4], ng[2][4];
    {
      const float* cp = fb + (size_t)nbase*64 + lg*8;
      const float* np = fb + (size_t)nbr[0]*64 + lg*8;
      cg[0][0] = *reinterpret_cast<const float4*>(cp);
      cg[0][1] = *reinterpret_cast<const float4*>(cp + 4);
      cg[0][2] = *reinterpret_cast<const float4*>(cp + 32);
      cg[0][3] = *reinterpret_cast<const float4*>(cp + 36);
      ng[0][0] = *reinterpret_cast<const float4*>(np);
      ng[0][1] = *reinterpret_cast<const float4*>(np + 4);
      ng[0][2] = *reinterpret_cast<const float4*>(np + 32);
      ng[0][3] = *reinterpret_cast<const float4*>(np + 36);
    }
    #pragma unroll
    for (int rg=0; rg<4; ++rg){
      if (rg < 3){   // prefetch next rg's gather (featsT is read-only: no hazard)
        const float* cp = fb + (size_t)(nbase + rg + 1)*64 + lg*8;
        const float* np = fb + (size_t)nbr[rg+1]*64 + lg*8;
        cg[(rg+1)&1][0] = *reinterpret_cast<const float4*>(cp);
        cg[(rg+1)&1][1] = *reinterpret_cast<const float4*>(cp + 4);
        cg[(rg+1)&1][2] = *reinterpret_cast<const float4*>(cp + 32);
        cg[(rg+1)&1][3] = *reinterpret_cast<const float4*>(cp + 36);
        ng[(rg+1)&1][0] = *reinterpret_cast<const float4*>(np);
        ng[(rg+1)&1][1] = *reinterpret_cast<const float4*>(np + 4);
        ng[(rg+1)&1][2] = *reinterpret_cast<const float4*>(np + 32);
        ng[(rg+1)&1][3] = *reinterpret_cast<const float4*>(np + 36);
      }
      float4 cl0 = cg[rg&1][0], cl1 = cg[rg&1][1], ch0 = cg[rg&1][2], ch1 = cg[rg&1][3];
      float4 nl0 = ng[rg&1][0], nl1 = ng[rg&1][1], nh0 = ng[rg&1][2], nh1 = ng[rg&1][3];
      bf16x8v afr[4];
      afr[0][0]=(__bf16)cl0.x; afr[0][1]=(__bf16)cl0.y; afr[0][2]=(__bf16)cl0.z; afr[0][3]=(__bf16)cl0.w;
      afr[0][4]=(__bf16)cl1.x; afr[0][5]=(__bf16)cl1.y; afr[0][6]=(__bf16)cl1.z; afr[0][7]=(__bf16)cl1.w;
      afr[1][0]=(__bf16)ch0.x; afr[1][1]=(__bf16)ch0.y; afr[1][2]=(__bf16)ch0.z; afr[1][3]=(__bf16)ch0.w;
      afr[1][4]=(__bf16)ch1.x; afr[1][5]=(__bf16)ch1.y; afr[1][6]=(__bf16)ch1.z; afr[1][7]=(__bf16)ch1.w;
      afr[2][0]=(__bf16)(nl0.x-cl0.x); afr[2][1]=(__bf16)(nl0.y-cl0.y);
      afr[2][2]=(__bf16)(nl0.z-cl0.z); afr[2][3]=(__bf16)(nl0.w-cl0.w);
      afr[2][4]=(__bf16)(nl1.x-cl1.x); afr[2][5]=(__bf16)(nl1.y-cl1.y);
      afr[2][6]=(__bf16)(nl1.z-cl1.z); afr[2][7]=(__bf16)(nl1.w-cl1.w);
      afr[3][0]=(__bf16)(nh0.x-ch0.x); afr[3][1]=(__bf16)(nh0.y-ch0.y);
      afr[3][2]=(__bf16)(nh0.z-ch0.z); afr[3][3]=(__bf16)(nh0.w-ch0.w);
      afr[3][4]=(__bf16)(nh1.x-ch1.x); afr[3][5]=(__bf16)(nh1.y-ch1.y);
      afr[3][6]=(__bf16)(nh1.z-ch1.z); afr[3][7]=(__bf16)(nh1.w-ch1.w);
      f32x4v acc[4] = {};
      #pragma unroll
      for (int kb=0; kb<4; ++kb){
        #pragma unroll
        for (int cf=0; cf<4; ++cf){
          uint4 b4 = *reinterpret_cast<const uint4*>(&Wl[((kb*8 + ch2*4 + cf)*64 + l)*8]);
          acc[cf] = __builtin_amdgcn_mfma_f32_16x16x32_bf16(afr[kb], __builtin_bit_cast(bf16x8v, b4), acc[cf], 0, 0, 0);
        }
      }
      scatter(acc);
      __syncthreads();       // keep identical phase structure (tb scatter -> read)
      store_tile(rg);
    }
  }

  // ---- cross-wave stats (red aliases tb; barrier first: all tb reads done) ----
  __syncthreads();
  #pragma unroll
  for (int cf=0; cf<4; ++cf){
    float s = ss[cf];
    s += __shfl_xor(s, 16);
    s += __shfl_xor(s, 32);
    float q = sq[cf];
    q += __shfl_xor(q, 16);
    q += __shfl_xor(q, 32);
    if (lg == 0){
      red[w*64 + cf*16 + li]        = s;
      red[512 + w*64 + cf*16 + li]  = q;
    }
  }
  __syncthreads();
  if (t < 128){
    int ch3 = t >> 6, col2 = t & 63;
    float s = red[(ch3*4+0)*64 + col2] + red[(ch3*4+1)*64 + col2]
            + red[(ch3*4+2)*64 + col2] + red[(ch3*4+3)*64 + col2];
    partials[(size_t)blockIdx.x*256 + t] = s;
  } else if (t < 256){
    int t3 = t - 128;
    int ch3 = t3 >> 6, col2 = t3 & 63;
    float q = red[512 + (ch3*4+0)*64 + col2] + red[512 + (ch3*4+1)*64 + col2]
            + red[512 + (ch3*4+2)*64 + col2] + red[512 + (ch3*4+3)*64 + col2];
    partials[(size_t)blockIdx.x*256 + 128 + t3] = q;
  }
}

// ---------------- shortcut GEMM: feats(64) x Wsc^T -> sc f32 ----------------
__global__ __launch_bounds__(256) void sc_gemm(const float* __restrict__ featsT,
                                               const float* __restrict__ W,
                                               float* __restrict__ scout,
                                               float* __restrict__ partials){
  __shared__ __align__(16) unsigned short Wt[64][136];
  __shared__ __align__(16) unsigned short xs[64][72];
  int t = threadIdx.x, tx = t&15, ty = t>>4;
  int rowbase = blockIdx.x * 64;
  for (int it=0; it<32; ++it){
    int flat = it*256 + t;
    int o = flat>>6, c = flat&63;
    Wt[c][o] = bfr(W[flat]);
  }
  for (int it=0; it<16; ++it){
    int flat = it*256 + t;
    int r = flat>>6, c = flat&63;
    xs[r][c] = bfr(featsT[(size_t)(rowbase + r)*64 + c]);
  }
  __syncthreads();
  float acc[4][8] = {};
  for (int c=0;c<64;++c){
    uint4 wv = *reinterpret_cast<const uint4*>(&Wt[c][tx*8]);
    float w[8];
    w[0]=bl(wv.x); w[1]=bh(wv.x); w[2]=bl(wv.y); w[3]=bh(wv.y);
    w[4]=bl(wv.z); w[5]=bh(wv.z); w[6]=bl(wv.w); w[7]=bh(wv.w);
    #pragma unroll
    for (int i=0;i<4;++i){
      float xv = bl((unsigned)xs[ty*4+i][c]);
      #pragma unroll
      for (int j=0;j<8;++j) acc[i][j] = fmaf(xv, w[j], acc[i][j]);
    }
  }
  #pragma unroll
  for (int i=0;i<4;++i)
    #pragma unroll
    for (int j=0;j<8;++j)
      scout[(size_t)(rowbase + ty*4 + i)*128 + tx*8 + j] = acc[i][j];

  __syncthreads();
  float* red = reinterpret_cast<float*>(&xs[0][0]);
  #pragma unroll
  for (int j=0;j<8;++j){
    float s=0.f;
    #pragma unroll
    for (int i=0;i<4;++i) s += acc[i][j];
    red[ty*128 + tx*8 + j] = s;
  }
  __syncthreads();
  if (t<128){
    float s=0.f;
    for (int y2=0;y2<16;++y2) s += red[y2*128 + t];
    partials[(size_t)blockIdx.x*256 + t] = s;
  }
  __syncthreads();
  #pragma unroll
  for (int j=0;j<8;++j){
    float s=0.f;
    #pragma unroll
    for (int i=0;i<4;++i) s += acc[i][j]*acc[i][j];
    red[ty*128 + tx*8 + j] = s;
  }
  __syncthreads();
  if (t<128){
    float s=0.f;
    for (int y2=0;y2<16;++y2) s += red[y2*128 + t];
    partials[(size_t)blockIdx.x*256 + 128 + t] = s;
  }
}

// ---------------- deterministic stat reduction ----------------
__global__ __launch_bounds__(256) void reduce_stage1(const float* __restrict__ partials,
                                                     float* __restrict__ out, int rows){
  int t = threadIdx.x;
  size_t base = (size_t)blockIdx.x * rows * 256;
  float acc = 0.f;
  for (int r=0;r<rows;++r) acc += partials[base + (size_t)r*256 + t];
  out[blockIdx.x*256 + t] = acc;
}

__global__ __launch_bounds__(256) void finalize_stats(const float* __restrict__ s1, int g1,
                                                      float inv_count,
                                                      const float* __restrict__ g,
                                                      const float* __restrict__ beta,
                                                      float* __restrict__ sb){
  int t = threadIdx.x;
  float acc = 0.f;
  for (int j=0;j<g1;++j) acc += s1[j*256 + t];
  __shared__ float tot[256];
  tot[t] = acc;
  __syncthreads();
  if (t < 128){
    float mean = tot[t] * inv_count;
    float var  = tot[128+t] * inv_count - mean*mean;
    var = fmaxf(var, 0.f);
    float rstd = 1.0f / sqrtf(var + 1e-5f);
    float s = g[t] * rstd;
    sb[t] = s;
    sb[128+t] = beta[t] - mean*s;
  }
}

// ---------------- final v2: vectorized y2 loads (uint4) ----------------
__global__ __launch_bounds__(256) void final_kernel(const unsigned short* __restrict__ y2,
                                                    const float* __restrict__ sc,
                                                    const float* __restrict__ sb2,
                                                    const float* __restrict__ sbsc,
                                                    float* __restrict__ out){
  __shared__ __align__(16) float obuf[64][130];
  int t = threadIdx.x;
  int b = blockIdx.x >> 4;
  int n0 = (blockIdx.x & 15) * 64;
  int oc = (t & 15) * 8;     // 8 consecutive channels per thread
  int nl0 = t >> 4;          // 16 rows per pass, 4 passes

  float4 s2a = *reinterpret_cast<const float4*>(sb2 + oc);
  float4 s2b = *reinterpret_cast<const float4*>(sb2 + oc + 4);
  float4 c2a = *reinterpret_cast<const float4*>(sb2 + 128 + oc);
  float4 c2b = *reinterpret_cast<const float4*>(sb2 + 128 + oc + 4);
  float4 ssa = *reinterpret_cast<const float4*>(sbsc + oc);
  float4 ssb = *reinterpret_cast<const float4*>(sbsc + oc + 4);
  float4 csa = *reinterpret_cast<const float4*>(sbsc + 128 + oc);
  float4 csb = *reinterpret_cast<const float4*>(sbsc + 128 + oc + 4);

  #pragma unroll
  for (int p=0; p<4; ++p){
    int nl = p*16 + nl0;
    size_t nglob = (size_t)((b<<10) + n0 + nl);
    const unsigned short* yp = y2 + (nglob<<4)*128 + oc;
    float a0=0,a1=0,a2=0,a3=0,a4=0,a5=0,a6=0,a7=0;
    #pragma unroll
    for (int k=0;k<16;++k){
      uint4 v = *reinterpret_cast<const uint4*>(yp + k*128);
      a0 += fmaxf(fmaf(bl(v.x), s2a.x, c2a.x), 0.f);
      a1 += fmaxf(fmaf(bh(v.x), s2a.y, c2a.y), 0.f);
      a2 += fmaxf(fmaf(bl(v.y), s2a.z, c2a.z), 0.f);
      a3 += fmaxf(fmaf(bh(v.y), s2a.w, c2a.w), 0.f);
      a4 += fmaxf(fmaf(bl(v.z), s2b.x, c2b.x), 0.f);
      a5 += fmaxf(fmaf(bh(v.z), s2b.y, c2b.y), 0.f);
      a6 += fmaxf(fmaf(bl(v.w), s2b.z, c2b.z), 0.f);
      a7 += fmaxf(fmaf(bh(v.w), s2b.w, c2b.w), 0.f);
    }
    const float* scp = sc + nglob*128 + oc;
    float4 v0 = *reinterpret_cast<const float4*>(scp);
    float4 v1 = *reinterpret_cast<const float4*>(scp + 4);
    float4 o0, o1;
    o0.x = fmaxf(fmaf(v0.x, ssa.x, csa.x) + a0*(1.f/16.f), 0.f);
    o0.y = fmaxf(fmaf(v0.y, ssa.y, csa.y) + a1*(1.f/16.f), 0.f);
    o0.z = fmaxf(fmaf(v0.z, ssa.z, csa.z) + a2*(1.f/16.f), 0.f);
    o0.w = fmaxf(fmaf(v0.w, ssa.w, csa.w) + a3*(1.f/16.f), 0.f);
    o1.x = fmaxf(fmaf(v1.x, ssb.x, csb.x) + a4*(1.f/16.f), 0.f);
    o1.y = fmaxf(fmaf(v1.y, ssb.y, csb.y) + a5*(1.f/16.f), 0.f);
    o1.z = fmaxf(fmaf(v1.z, ssb.z, csb.z) + a6*(1.f/16.f), 0.f);
    o1.w = fmaxf(fmaf(v1.w, ssb.w, csb.w) + a7*(1.f/16.f), 0.f);
    *reinterpret_cast<float4*>(&obuf[nl][oc])     = o0;
    *reinterpret_cast<float4*>(&obuf[nl][oc + 4]) = o1;
  }
  __syncthreads();
  for (int it=0; it<32; ++it){
    int flat = it*256 + t;
    int oo = flat>>6, nl = flat&63;
    out[((size_t)b<<17) + (oo<<10) + n0 + nl] = obuf[nl][oo];
  }
}

extern "C" void kernel_launch(void* const* d_in, const int* in_sizes, int n_in,
                              void* d_out, int out_size, void* d_ws, size_t ws_size,
                              hipStream_t stream) {
  const float* points   = (const float*)d_in[0];
  const float* features = (const float*)d_in[1];
  const float* W0  = (const float*)d_in[2];
  const float* g0  = (const float*)d_in[3];
  const float* b0  = (const float*)d_in[4];
  const float* W1  = (const float*)d_in[5];
  const float* g1  = (const float*)d_in[6];
  const float* b1  = (const float*)d_in[7];
  const float* W2  = (const float*)d_in[8];
  const float* g2  = (const float*)d_in[9];
  const float* b2  = (const float*)d_in[10];
  const float* Wsc = (const float*)d_in[11];
  const float* gsc = (const float*)d_in[12];
  const float* bsc = (const float*)d_in[13];

  float* out = (float*)d_out;

  if (ws_size < WS_NEED){
    float v = (float)(ws_size >> 20);
    sentinel_kernel<<<(out_size + 255)/256, 256, 0, stream>>>(out, out_size, v);
    return;
  }

  char* ws = (char*)d_ws;
  float*          featsT = (float*)(ws + OFF_FT);
  int*            idx    = (int*)(ws + OFF_IDX);
  unsigned short* y      = (unsigned short*)(ws + OFF_Y);
  float*          scbuf  = (float*)(ws + OFF_SC);
  float*          part   = (float*)(ws + OFF_PART);
  unsigned short* WB     = (unsigned short*)(ws + OFF_WB);
  float*          s1     = (float*)(ws + OFF_S1);
  float*          sb     = (float*)(ws + OFF_SB);

  transpose_feats<<<dim3(32,16), 256, 0, stream>>>(features, featsT);
  convert_w<<<24, 256, 0, stream>>>(W0, W1, W2, WB);
  knn_kernel<<<dim3(32,32), 256, 0, stream>>>(points, idx);

  // layer 0 (gather + MFMA)
  gemm7<0><<<NROW/256, 512, 0, stream>>>(featsT, idx, nullptr, nullptr, WB, y, part);
  reduce_stage1<<<64, 256, 0, stream>>>(part, s1, 32);
  finalize_stats<<<1, 256, 0, stream>>>(s1, 64, 1.f/524288.f, g0, b0, sb + 0);
  // layer 1 (in-place)
  gemm7<1><<<NROW/256, 512, 0, stream>>>(nullptr, nullptr, y, sb + 0, WB + 16384, y, part);
  reduce_stage1<<<64, 256, 0, stream>>>(part, s1, 32);
  finalize_stats<<<1, 256, 0, stream>>>(s1, 64, 1.f/524288.f, g1, b1, sb + 256);
  // layer 2 (in-place)
  gemm7<1><<<NROW/256, 512, 0, stream>>>(nullptr, nullptr, y, sb + 256, WB + 32768, y, part);
  reduce_stage1<<<64, 256, 0, stream>>>(part, s1, 32);
  finalize_stats<<<1, 256, 0, stream>>>(s1, 64, 1.f/524288.f, g2, b2, sb + 512);
  // shortcut
  sc_gemm<<<NROWSC/64, 256, 0, stream>>>(featsT, Wsc, scbuf, part);
  reduce_stage1<<<8, 256, 0, stream>>>(part, s1, 64);
  finalize_stats<<<1, 256, 0, stream>>>(s1, 8, 1.f/32768.f, gsc, bsc, sb + 768);
  // fuse + transpose
  final_kernel<<<512, 256, 0, stream>>>(y, scbuf, sb + 512, sb + 768, out);
}

// Round 17
// 376.551 us; speedup vs baseline: 2.3099x; 2.3099x over previous
//
#include <hip/hip_runtime.h>

// EdgeConvBlock: B=32, N=1024, D=3, CIN=64, K=16, COUT=128x3
// Round 17: exact revert to round-15 best (377us). r16's 512-thread col-split
// regressed via launch_bounds(512,6) VGPR cap (40 regs) -> full spill
// (WRITE 133->649MB). gemm4: W in LDS, 1-ahead prefetch; final_kernel vectorized.

#define BB 32
#define NN 1024
#define CINC 64
#define KK 16
#define CO 128
#define NROW (BB*NN*KK)   // 524288
#define NROWSC (BB*NN)    // 32768

// ---- ws layout (bytes) ----
static const size_t OFF_FT   = 0;            // featsT f32 [B][N][64]       8,388,608
static const size_t OFF_IDX  = 8388608;      // idx int  [B][N][16]         2,097,152
static const size_t OFF_Y    = 10485760;     // y  bf16  [NROW][128]      134,217,728
static const size_t OFF_SC   = 144703488;    // sc f32   [NROWSC][128]     16,777,216
static const size_t OFF_PART = 161480704;    // partials f32 [2048][256] (2MB used of 8MB)
static const size_t OFF_WB   = 165675008;    // swizzled bf16 W [3][16384]     98,304
static const size_t OFF_S1   = 169869312;    // stage1 f32 [64][256]           65,536
static const size_t OFF_SB   = 169934848;    // scale/bias f32 [4][256]         4,096
static const size_t WS_NEED  = 169938944;

typedef __bf16 bf16x8v __attribute__((ext_vector_type(8)));
typedef float  f32x4v  __attribute__((ext_vector_type(4)));

__device__ __forceinline__ float bl(unsigned u){ return __uint_as_float(u<<16); }
__device__ __forceinline__ float bh(unsigned u){ return __uint_as_float(u & 0xffff0000u); }
__device__ __forceinline__ unsigned short bfr(float x){
  unsigned u = __float_as_uint(x);
  u += 0x7fffu + ((u>>16)&1u);
  return (unsigned short)(u>>16);
}
__device__ __forceinline__ unsigned short b16(float x){
  return __builtin_bit_cast(unsigned short, (__bf16)x);   // HW RNE convert
}

// ---------------- diagnostic sentinel ----------------
__global__ __launch_bounds__(256) void sentinel_kernel(float* __restrict__ out, int n, float v){
  int i = blockIdx.x*256 + threadIdx.x;
  if (i < n) out[i] = v;
}

// ---------------- transpose features (b,c,n) -> (b,n,c) ----------------
__global__ __launch_bounds__(256) void transpose_feats(const float* __restrict__ f,
                                                       float* __restrict__ ft){
  __shared__ __align__(16) float tile[64][65];
  int t = threadIdx.x;
  int b = blockIdx.x, n0 = blockIdx.y*64;
  for (int it=0; it<16; ++it){
    int flat = it*256 + t;
    int c = flat>>6, nl = flat&63;
    tile[c][nl] = f[(b*64 + c)*1024 + n0 + nl];
  }
  __syncthreads();
  for (int it=0; it<16; ++it){
    int flat = it*256 + t;
    int nl = flat>>6, c = flat&63;
    ft[((b<<10) + n0 + nl)*64 + c] = tile[c][nl];
  }
}

// ---------------- weight pre-swizzle: W[o][c] f32 -> bf16 frag order ----------------
// WB[lay][ (kb*8+cf)*64 + l ][j] = W[cf*16 + (l&15)][kb*32 + (l>>4)*8 + j]
__global__ __launch_bounds__(256) void convert_w(const float* __restrict__ W0,
                                                 const float* __restrict__ W1,
                                                 const float* __restrict__ W2,
                                                 unsigned short* __restrict__ WB){
  int tid = blockIdx.x*256 + threadIdx.x;      // 0..6143
  int lay = tid >> 11, rem = tid & 2047;
  int f = rem >> 6, l = rem & 63;
  int kb = f >> 3, cf = f & 7;
  int li = l & 15, lg = l >> 4;
  const float* Ws = lay==0 ? W0 : (lay==1 ? W1 : W2);
  int o = cf*16 + li;
  unsigned short p[8];
  #pragma unroll
  for (int j=0;j<8;++j) p[j] = bfr(Ws[o*128 + kb*32 + lg*8 + j]);
  uint4 o4;
  o4.x = (unsigned)p[0] | ((unsigned)p[1]<<16);
  o4.y = (unsigned)p[2] | ((unsigned)p[3]<<16);
  o4.z = (unsigned)p[4] | ((unsigned)p[5]<<16);
  o4.w = (unsigned)p[6] | ((unsigned)p[7]<<16);
  *reinterpret_cast<uint4*>(WB + (size_t)lay*16384 + (size_t)rem*8) = o4;
}

// ---------------- KNN v4: packed-key cascade, 32 queries x 8 chunks of 128 ----------------
// key = positive normal double: [bit62=1][fkey32(pd)][tie=1023-m] -> f64 order == top_k order.
__global__ __launch_bounds__(256) void knn_kernel(const float* __restrict__ pts,
                                                  int* __restrict__ idxout){
  __shared__ __align__(16) char smem[34816];
  float4* p4 = (float4*)smem;                          // [1024] during scan
  unsigned long long (*mk)[32][17] =
      (unsigned long long(*)[32][17])smem;             // [8][32][17] keys after scan

  int t = threadIdx.x;
  int b = blockIdx.x, g = blockIdx.y;
  for (int i=t; i<1024; i+=256){
    float a = pts[(b*3+0)*1024+i];
    float c = pts[(b*3+1)*1024+i];
    float d = pts[(b*3+2)*1024+i];
    float xx = __fadd_rn(__fadd_rn(__fmul_rn(a,a), __fmul_rn(c,c)), __fmul_rn(d,d));
    p4[i] = make_float4(a, c, d, xx);
  }
  __syncthreads();

  int q = t & 31, c = t >> 5;       // query-in-block, chunk
  int n = g*32 + q;
  float4 qp = p4[n];
  float qx=qp.x, qy=qp.y, qz=qp.z, qxx=qp.w;
  double vals[16];
  #pragma unroll
  for (int j=0;j<16;++j) vals[j] = 0.0;

  int m0 = c*128;
  for (int i0=0; i0<128; i0+=4){
    float4 cand[4];
    #pragma unroll
    for (int u=0;u<4;++u) cand[u] = p4[m0 + i0 + u];
    #pragma unroll
    for (int u=0;u<4;++u){
      int m = m0 + i0 + u;
      float inner = __fadd_rn(__fadd_rn(__fmul_rn(qx,cand[u].x), __fmul_rn(qy,cand[u].y)), __fmul_rn(qz,cand[u].z));
      float pd = __fsub_rn(__fsub_rn(__fmul_rn(2.0f, inner), qxx), cand[u].w);
      unsigned uv = __float_as_uint(pd);
      unsigned fk = uv ^ (0x80000000u | (unsigned)((int)uv >> 31));  // monotone f32->u32
      unsigned lo = (fk << 20) | (unsigned)(1023 - m);
      unsigned hi = 0x40000000u | (fk >> 12);
      hi = (m == n) ? 0u : hi;                                       // self -> tiny key
      double key = __builtin_bit_cast(double, ((unsigned long long)hi << 32) | lo);
      #pragma unroll
      for (int j=0;j<16;++j){
        double mx = fmax(vals[j], key);
        key = fmin(vals[j], key);
        vals[j] = mx;
      }
    }
  }
  __syncthreads();                    // scans done; points dead -> key lists live
  #pragma unroll
  for (int j=0;j<16;++j) mk[c][q][j] = __builtin_bit_cast(unsigned long long, vals[j]);
  mk[c][q][16] = 0ull;                // sentinel
  __syncthreads();

  if (t < 32){
    int qq = t;
    int p0=0,p1=0,p2=0,p3=0,p4i=0,p5=0,p6=0,p7=0;
    unsigned long long v0=mk[0][qq][0], v1=mk[1][qq][0], v2=mk[2][qq][0], v3=mk[3][qq][0];
    unsigned long long v4=mk[4][qq][0], v5=mk[5][qq][0], v6=mk[6][qq][0], v7=mk[7][qq][0];
    int* dst = idxout + ((size_t)((b<<10) + g*32 + qq))*16;
    #pragma unroll
    for (int j=0;j<16;++j){
      unsigned long long best = v0; int bc = 0;
      if (v1 > best){ best = v1; bc = 1; }
      if (v2 > best){ best = v2; bc = 2; }
      if (v3 > best){ best = v3; bc = 3; }
      if (v4 > best){ best = v4; bc = 4; }
      if (v5 > best){ best = v5; bc = 5; }
      if (v6 > best){ best = v6; bc = 6; }
      if (v7 > best){ best = v7; bc = 7; }
      dst[j] = 1023 - (int)(best & 1023ull);
      if      (bc==0){ ++p0; v0 = mk[0][qq][p0]; }
      else if (bc==1){ ++p1; v1 = mk[1][qq][p1]; }
      else if (bc==2){ ++p2; v2 = mk[2][qq][p2]; }
      else if (bc==3){ ++p3; v3 = mk[3][qq][p3]; }
      else if (bc==4){ ++p4i; v4 = mk[4][qq][p4i]; }
      else if (bc==5){ ++p5; v5 = mk[5][qq][p5]; }
      else if (bc==6){ ++p6; v6 = mk[6][qq][p6]; }
      else           { ++p7; v7 = mk[7][qq][p7]; }
    }
  }
}

// ---------------- GEMM v4 (r12/r15 best): 256x128 per block, K=128, 1-ahead prefetch ----------------
// MODE 0: x = (center || nbr-center); MODE 1: x = relu(yin*s+b), in-place safe.
template<int MODE>
__global__ __launch_bounds__(256, 2) void gemm4(const float* __restrict__ featsT,
                                                const int* __restrict__ knnidx,
                                                const unsigned short* yin,
                                                const float* __restrict__ sb,
                                                const unsigned short* __restrict__ Wswz,
                                                unsigned short* yout,
                                                float* __restrict__ partials){
  __shared__ __align__(16) unsigned short Wl[16384];       // 32KB swizzled W
  __shared__ __align__(16) unsigned short tb[4][16][132];  // 16.9KB per-wave transpose
  float* red = (float*)&tb[0][0][0];                       // 4KB alias (used after barrier)

  int t = threadIdx.x;
  int w = t >> 6, l = t & 63;
  int li = l & 15, lg = l >> 4;

  // stage swizzled W: linear 32KB copy
  #pragma unroll
  for (int it=0; it<8; ++it){
    int v = it*256 + t;
    *reinterpret_cast<uint4*>(&Wl[v*8]) =
      *reinterpret_cast<const uint4*>(Wswz + (size_t)v*8);
  }
  __syncthreads();

  float ss[8] = {0.f,0.f,0.f,0.f,0.f,0.f,0.f,0.f};
  float sq[8] = {0.f,0.f,0.f,0.f,0.f,0.f,0.f,0.f};

  // -------- epilogue (shared by both modes) --------
  auto epilogue = [&](int rg, f32x4v (&acc)[8]){
    size_t rbase = (size_t)blockIdx.x*256 + w*64 + rg*16;
    #pragma unroll
    for (int cf=0; cf<8; ++cf){
      ss[cf] += acc[cf][0]+acc[cf][1]+acc[cf][2]+acc[cf][3];
      sq[cf] += acc[cf][0]*acc[cf][0]+acc[cf][1]*acc[cf][1]+acc[cf][2]*acc[cf][2]+acc[cf][3]*acc[cf][3];
    }
    #pragma unroll
    for (int cf=0; cf<8; ++cf){
      tb[w][lg*4 + 0][cf*16 + li] = b16(acc[cf][0]);
      tb[w][lg*4 + 1][cf*16 + li] = b16(acc[cf][1]);
      tb[w][lg*4 + 2][cf*16 + li] = b16(acc[cf][2]);
      tb[w][lg*4 + 3][cf*16 + li] = b16(acc[cf][3]);
    }
    __builtin_amdgcn_wave_barrier();   // scatter writes before cross-lane reads
    {
      int row4 = l >> 4, ch = l & 15;
      #pragma unroll
      for (int s2=0; s2<4; ++s2){
        const unsigned short* src = &tb[w][s2*4 + row4][ch*8];
        unsigned short* dst = yout + (rbase + s2*4 + row4)*128 + ch*8;
        *reinterpret_cast<uint4*>(dst) = *reinterpret_cast<const uint4*>(src);
      }
    }
    __builtin_amdgcn_wave_barrier();   // reads done before next rg's scatter
  };

  if constexpr (MODE == 1){
    const unsigned short* ybase = yin + ((size_t)blockIdx.x*256 + w*64 + li)*128 + lg*8;
    uint4 yb[2][4];
    #pragma unroll
    for (int kb=0; kb<4; ++kb)
      yb[0][kb] = *reinterpret_cast<const uint4*>(ybase + kb*32);
    #pragma unroll
    for (int rg=0; rg<4; ++rg){
      if (rg < 3){   // 1-ahead prefetch (issued before any compute/barrier of this rg)
        #pragma unroll
        for (int kb=0; kb<4; ++kb)
          yb[(rg+1)&1][kb] = *reinterpret_cast<const uint4*>(ybase + (size_t)(rg+1)*2048 + kb*32);
      }
      f32x4v acc[8] = {};
      #pragma unroll
      for (int kb=0; kb<4; ++kb){
        int c0 = kb*32 + lg*8;
        uint4 yv = yb[rg&1][kb];
        float4 s0 = *reinterpret_cast<const float4*>(sb + c0);
        float4 s1 = *reinterpret_cast<const float4*>(sb + c0 + 4);
        float4 b0 = *reinterpret_cast<const float4*>(sb + 128 + c0);
        float4 b1 = *reinterpret_cast<const float4*>(sb + 128 + c0 + 4);
        bf16x8v av;
        av[0] = (__bf16)fmaxf(fmaf(bl(yv.x), s0.x, b0.x), 0.f);
        av[1] = (__bf16)fmaxf(fmaf(bh(yv.x), s0.y, b0.y), 0.f);
        av[2] = (__bf16)fmaxf(fmaf(bl(yv.y), s0.z, b0.z), 0.f);
        av[3] = (__bf16)fmaxf(fmaf(bh(yv.y), s0.w, b0.w), 0.f);
        av[4] = (__bf16)fmaxf(fmaf(bl(yv.z), s1.x, b1.x), 0.f);
        av[5] = (__bf16)fmaxf(fmaf(bh(yv.z), s1.y, b1.y), 0.f);
        av[6] = (__bf16)fmaxf(fmaf(bl(yv.w), s1.z, b1.z), 0.f);
        av[7] = (__bf16)fmaxf(fmaf(bh(yv.w), s1.w, b1.w), 0.f);
        #pragma unroll
        for (int cf=0; cf<8; ++cf){
          uint4 b4 = *reinterpret_cast<const uint4*>(&Wl[((kb*8+cf)*64 + l)*8]);
          acc[cf] = __builtin_amdgcn_mfma_f32_16x16x32_bf16(av, __builtin_bit_cast(bf16x8v, b4), acc[cf], 0, 0, 0);
        }
      }
      epilogue(rg, acc);
    }
  } else {
    int b = blockIdx.x >> 6;                     // 64 blocks per batch
    int nbase = (blockIdx.x & 63)*16 + w*4;      // point n for rg = nbase + rg
    const float* fb = featsT + (((size_t)b)<<10)*64;
    int nbr[4];
    #pragma unroll
    for (int rg=0; rg<4; ++rg)
      nbr[rg] = knnidx[((size_t)((b<<10) + nbase + rg))*16 + li];
    float4 cg[2][4], ng[2][4];
    {
      const float* cp = fb + (size_t)nbase*64 + lg*8;
      const float* np = fb + (size_t)nbr[0]*64 + lg*8;
      cg[0][0] = *reinterpret_cast<const float4*>(cp);
      cg[0][1] = *reinterpret_cast<const float4*>(cp + 4);
      cg[0][2] = *reinterpret_cast<const float4*>(cp + 32);
      cg[0][3] = *reinterpret_cast<const float4*>(cp + 36);
      ng[0][0] = *reinterpret_cast<const float4*>(np);
      ng[0][1] = *reinterpret_cast<const float4*>(np + 4);
      ng[0][2] = *reinterpret_cast<const float4*>(np + 32);
      ng[0][3] = *reinterpret_cast<const float4*>(np + 36);
    }
    #pragma unroll
    for (int rg=0; rg<4; ++rg){
      if (rg < 3){   // prefetch next rg's gather
        const float* cp = fb + (size_t)(nbase + rg + 1)*64 + lg*8;
        const float* np = fb + (size_t)nbr[rg+1]*64 + lg*8;
        cg[(rg+1)&1][0] = *reinterpret_cast<const float4*>(cp);
        cg[(rg+1)&1][1] = *reinterpret_cast<const float4*>(cp + 4);
        cg[(rg+1)&1][2] = *reinterpret_cast<const float4*>(cp + 32);
        cg[(rg+1)&1][3] = *reinterpret_cast<const float4*>(cp + 36);
        ng[(rg+1)&1][0] = *reinterpret_cast<const float4*>(np);
        ng[(rg+1)&1][1] = *reinterpret_cast<const float4*>(np + 4);
        ng[(rg+1)&1][2] = *reinterpret_cast<const float4*>(np + 32);
        ng[(rg+1)&1][3] = *reinterpret_cast<const float4*>(np + 36);
      }
      float4 cl0 = cg[rg&1][0], cl1 = cg[rg&1][1], ch0 = cg[rg&1][2], ch1 = cg[rg&1][3];
      float4 nl0 = ng[rg&1][0], nl1 = ng[rg&1][1], nh0 = ng[rg&1][2], nh1 = ng[rg&1][3];
      bf16x8v afr[4];
      afr[0][0]=(__bf16)cl0.x; afr[0][1]=(__bf16)cl0.y; afr[0][2]=(__bf16)cl0.z; afr[0][3]=(__bf16)cl0.w;
      afr[0][4]=(__bf16)cl1.x; afr[0][5]=(__bf16)cl1.y; afr[0][6]=(__bf16)cl1.z; afr[0][7]=(__bf16)cl1.w;
      afr[1][0]=(__bf16)ch0.x; afr[1][1]=(__bf16)ch0.y; afr[1][2]=(__bf16)ch0.z; afr[1][3]=(__bf16)ch0.w;
      afr[1][4]=(__bf16)ch1.x; afr[1][5]=(__bf16)ch1.y; afr[1][6]=(__bf16)ch1.z; afr[1][7]=(__bf16)ch1.w;
      afr[2][0]=(__bf16)(nl0.x-cl0.x); afr[2][1]=(__bf16)(nl0.y-cl0.y);
      afr[2][2]=(__bf16)(nl0.z-cl0.z); afr[2][3]=(__bf16)(nl0.w-cl0.w);
      afr[2][4]=(__bf16)(nl1.x-cl1.x); afr[2][5]=(__bf16)(nl1.y-cl1.y);
      afr[2][6]=(__bf16)(nl1.z-cl1.z); afr[2][7]=(__bf16)(nl1.w-cl1.w);
      afr[3][0]=(__bf16)(nh0.x-ch0.x); afr[3][1]=(__bf16)(nh0.y-ch0.y);
      afr[3][2]=(__bf16)(nh0.z-ch0.z); afr[3][3]=(__bf16)(nh0.w-ch0.w);
      afr[3][4]=(__bf16)(nh1.x-ch1.x); afr[3][5]=(__bf16)(nh1.y-ch1.y);
      afr[3][6]=(__bf16)(nh1.z-ch1.z); afr[3][7]=(__bf16)(nh1.w-ch1.w);
      f32x4v acc[8] = {};
      #pragma unroll
      for (int kb=0; kb<4; ++kb){
        #pragma unroll
        for (int cf=0; cf<8; ++cf){
          uint4 b4 = *reinterpret_cast<const uint4*>(&Wl[((kb*8+cf)*64 + l)*8]);
          acc[cf] = __builtin_amdgcn_mfma_f32_16x16x32_bf16(afr[kb], __builtin_bit_cast(bf16x8v, b4), acc[cf], 0, 0, 0);
        }
      }
      epilogue(rg, acc);
    }
  }

  // ---- cross-wave stats (red aliases tb; barrier first) ----
  __syncthreads();
  #pragma unroll
  for (int cf=0; cf<8; ++cf){
    float s = ss[cf];
    s += __shfl_xor(s, 16);
    s += __shfl_xor(s, 32);
    float q = sq[cf];
    q += __shfl_xor(q, 16);
    q += __shfl_xor(q, 32);
    if (lg == 0){
      red[w*128 + cf*16 + li]       = s;
      red[512 + w*128 + cf*16 + li] = q;
    }
  }
  __syncthreads();
  {
    int col = t & 127;
    int base = (t >> 7) * 512;
    float s = red[base + col] + red[base + 128 + col] + red[base + 256 + col] + red[base + 384 + col];
    partials[(size_t)blockIdx.x*256 + (t>>7)*128 + col] = s;
  }
}

// ---------------- shortcut GEMM: feats(64) x Wsc^T -> sc f32 ----------------
__global__ __launch_bounds__(256) void sc_gemm(const float* __restrict__ featsT,
                                               const float* __restrict__ W,
                                               float* __restrict__ scout,
                                               float* __restrict__ partials){
  __shared__ __align__(16) unsigned short Wt[64][136];
  __shared__ __align__(16) unsigned short xs[64][72];
  int t = threadIdx.x, tx = t&15, ty = t>>4;
  int rowbase = blockIdx.x * 64;
  for (int it=0; it<32; ++it){
    int flat = it*256 + t;
    int o = flat>>6, c = flat&63;
    Wt[c][o] = bfr(W[flat]);
  }
  for (int it=0; it<16; ++it){
    int flat = it*256 + t;
    int r = flat>>6, c = flat&63;
    xs[r][c] = bfr(featsT[(size_t)(rowbase + r)*64 + c]);
  }
  __syncthreads();
  float acc[4][8] = {};
  for (int c=0;c<64;++c){
    uint4 wv = *reinterpret_cast<const uint4*>(&Wt[c][tx*8]);
    float w[8];
    w[0]=bl(wv.x); w[1]=bh(wv.x); w[2]=bl(wv.y); w[3]=bh(wv.y);
    w[4]=bl(wv.z); w[5]=bh(wv.z); w[6]=bl(wv.w); w[7]=bh(wv.w);
    #pragma unroll
    for (int i=0;i<4;++i){
      float xv = bl((unsigned)xs[ty*4+i][c]);
      #pragma unroll
      for (int j=0;j<8;++j) acc[i][j] = fmaf(xv, w[j], acc[i][j]);
    }
  }
  #pragma unroll
  for (int i=0;i<4;++i)
    #pragma unroll
    for (int j=0;j<8;++j)
      scout[(size_t)(rowbase + ty*4 + i)*128 + tx*8 + j] = acc[i][j];

  __syncthreads();
  float* red = reinterpret_cast<float*>(&xs[0][0]);
  #pragma unroll
  for (int j=0;j<8;++j){
    float s=0.f;
    #pragma unroll
    for (int i=0;i<4;++i) s += acc[i][j];
    red[ty*128 + tx*8 + j] = s;
  }
  __syncthreads();
  if (t<128){
    float s=0.f;
    for (int y2=0;y2<16;++y2) s += red[y2*128 + t];
    partials[(size_t)blockIdx.x*256 + t] = s;
  }
  __syncthreads();
  #pragma unroll
  for (int j=0;j<8;++j){
    float s=0.f;
    #pragma unroll
    for (int i=0;i<4;++i) s += acc[i][j]*acc[i][j];
    red[ty*128 + tx*8 + j] = s;
  }
  __syncthreads();
  if (t<128){
    float s=0.f;
    for (int y2=0;y2<16;++y2) s += red[y2*128 + t];
    partials[(size_t)blockIdx.x*256 + 128 + t] = s;
  }
}

// ---------------- deterministic stat reduction ----------------
__global__ __launch_bounds__(256) void reduce_stage1(const float* __restrict__ partials,
                                                     float* __restrict__ out, int rows){
  int t = threadIdx.x;
  size_t base = (size_t)blockIdx.x * rows * 256;
  float acc = 0.f;
  for (int r=0;r<rows;++r) acc += partials[base + (size_t)r*256 + t];
  out[blockIdx.x*256 + t] = acc;
}

__global__ __launch_bounds__(256) void finalize_stats(const float* __restrict__ s1, int g1,
                                                      float inv_count,
                                                      const float* __restrict__ g,
                                                      const float* __restrict__ beta,
                                                      float* __restrict__ sb){
  int t = threadIdx.x;
  float acc = 0.f;
  for (int j=0;j<g1;++j) acc += s1[j*256 + t];
  __shared__ float tot[256];
  tot[t] = acc;
  __syncthreads();
  if (t < 128){
    float mean = tot[t] * inv_count;
    float var  = tot[128+t] * inv_count - mean*mean;
    var = fmaxf(var, 0.f);
    float rstd = 1.0f / sqrtf(var + 1e-5f);
    float s = g[t] * rstd;
    sb[t] = s;
    sb[128+t] = beta[t] - mean*s;
  }
}

// ---------------- final v2: vectorized y2 loads (uint4) ----------------
__global__ __launch_bounds__(256) void final_kernel(const unsigned short* __restrict__ y2,
                                                    const float* __restrict__ sc,
                                                    const float* __restrict__ sb2,
                                                    const float* __restrict__ sbsc,
                                                    float* __restrict__ out){
  __shared__ __align__(16) float obuf[64][130];
  int t = threadIdx.x;
  int b = blockIdx.x >> 4;
  int n0 = (blockIdx.x & 15) * 64;
  int oc = (t & 15) * 8;     // 8 consecutive channels per thread
  int nl0 = t >> 4;          // 16 rows per pass, 4 passes

  float4 s2a = *reinterpret_cast<const float4*>(sb2 + oc);
  float4 s2b = *reinterpret_cast<const float4*>(sb2 + oc + 4);
  float4 c2a = *reinterpret_cast<const float4*>(sb2 + 128 + oc);
  float4 c2b = *reinterpret_cast<const float4*>(sb2 + 128 + oc + 4);
  float4 ssa = *reinterpret_cast<const float4*>(sbsc + oc);
  float4 ssb = *reinterpret_cast<const float4*>(sbsc + oc + 4);
  float4 csa = *reinterpret_cast<const float4*>(sbsc + 128 + oc);
  float4 csb = *reinterpret_cast<const float4*>(sbsc + 128 + oc + 4);

  #pragma unroll
  for (int p=0; p<4; ++p){
    int nl = p*16 + nl0;
    size_t nglob = (size_t)((b<<10) + n0 + nl);
    const unsigned short* yp = y2 + (nglob<<4)*128 + oc;
    float a0=0,a1=0,a2=0,a3=0,a4=0,a5=0,a6=0,a7=0;
    #pragma unroll
    for (int k=0;k<16;++k){
      uint4 v = *reinterpret_cast<const uint4*>(yp + k*128);
      a0 += fmaxf(fmaf(bl(v.x), s2a.x, c2a.x), 0.f);
      a1 += fmaxf(fmaf(bh(v.x), s2a.y, c2a.y), 0.f);
      a2 += fmaxf(fmaf(bl(v.y), s2a.z, c2a.z), 0.f);
      a3 += fmaxf(fmaf(bh(v.y), s2a.w, c2a.w), 0.f);
      a4 += fmaxf(fmaf(bl(v.z), s2b.x, c2b.x), 0.f);
      a5 += fmaxf(fmaf(bh(v.z), s2b.y, c2b.y), 0.f);
      a6 += fmaxf(fmaf(bl(v.w), s2b.z, c2b.z), 0.f);
      a7 += fmaxf(fmaf(bh(v.w), s2b.w, c2b.w), 0.f);
    }
    const float* scp = sc + nglob*128 + oc;
    float4 v0 = *reinterpret_cast<const float4*>(scp);
    float4 v1 = *reinterpret_cast<const float4*>(scp + 4);
    float4 o0, o1;
    o0.x = fmaxf(fmaf(v0.x, ssa.x, csa.x) + a0*(1.f/16.f), 0.f);
    o0.y = fmaxf(fmaf(v0.y, ssa.y, csa.y) + a1*(1.f/16.f), 0.f);
    o0.z = fmaxf(fmaf(v0.z, ssa.z, csa.z) + a2*(1.f/16.f), 0.f);
    o0.w = fmaxf(fmaf(v0.w, ssa.w, csa.w) + a3*(1.f/16.f), 0.f);
    o1.x = fmaxf(fmaf(v1.x, ssb.x, csb.x) + a4*(1.f/16.f), 0.f);
    o1.y = fmaxf(fmaf(v1.y, ssb.y, csb.y) + a5*(1.f/16.f), 0.f);
    o1.z = fmaxf(fmaf(v1.z, ssb.z, csb.z) + a6*(1.f/16.f), 0.f);
    o1.w = fmaxf(fmaf(v1.w, ssb.w, csb.w) + a7*(1.f/16.f), 0.f);
    *reinterpret_cast<float4*>(&obuf[nl][oc])     = o0;
    *reinterpret_cast<float4*>(&obuf[nl][oc + 4]) = o1;
  }
  __syncthreads();
  for (int it=0; it<32; ++it){
    int flat = it*256 + t;
    int oo = flat>>6, nl = flat&63;
    out[((size_t)b<<17) + (oo<<10) + n0 + nl] = obuf[nl][oo];
  }
}

extern "C" void kernel_launch(void* const* d_in, const int* in_sizes, int n_in,
                              void* d_out, int out_size, void* d_ws, size_t ws_size,
                              hipStream_t stream) {
  const float* points   = (const float*)d_in[0];
  const float* features = (const float*)d_in[1];
  const float* W0  = (const float*)d_in[2];
  const float* g0  = (const float*)d_in[3];
  const float* b0  = (const float*)d_in[4];
  const float* W1  = (const float*)d_in[5];
  const float* g1  = (const float*)d_in[6];
  const float* b1  = (const float*)d_in[7];
  const float* W2  = (const float*)d_in[8];
  const float* g2  = (const float*)d_in[9];
  const float* b2  = (const float*)d_in[10];
  const float* Wsc = (const float*)d_in[11];
  const float* gsc = (const float*)d_in[12];
  const float* bsc = (const float*)d_in[13];

  float* out = (float*)d_out;

  if (ws_size < WS_NEED){
    float v = (float)(ws_size >> 20);
    sentinel_kernel<<<(out_size + 255)/256, 256, 0, stream>>>(out, out_size, v);
    return;
  }

  char* ws = (char*)d_ws;
  float*          featsT = (float*)(ws + OFF_FT);
  int*            idx    = (int*)(ws + OFF_IDX);
  unsigned short* y      = (unsigned short*)(ws + OFF_Y);
  float*          scbuf  = (float*)(ws + OFF_SC);
  float*          part   = (float*)(ws + OFF_PART);
  unsigned short* WB     = (unsigned short*)(ws + OFF_WB);
  float*          s1     = (float*)(ws + OFF_S1);
  float*          sb     = (float*)(ws + OFF_SB);

  transpose_feats<<<dim3(32,16), 256, 0, stream>>>(features, featsT);
  convert_w<<<24, 256, 0, stream>>>(W0, W1, W2, WB);
  knn_kernel<<<dim3(32,32), 256, 0, stream>>>(points, idx);

  // layer 0 (gather + MFMA, W in LDS pre-swizzled, pipelined gather)
  gemm4<0><<<NROW/256, 256, 0, stream>>>(featsT, idx, nullptr, nullptr, WB, y, part);
  reduce_stage1<<<64, 256, 0, stream>>>(part, s1, 32);
  finalize_stats<<<1, 256, 0, stream>>>(s1, 64, 1.f/524288.f, g0, b0, sb + 0);
  // layer 1 (in-place, 1-ahead y prefetch)
  gemm4<1><<<NROW/256, 256, 0, stream>>>(nullptr, nullptr, y, sb + 0, WB + 16384, y, part);
  reduce_stage1<<<64, 256, 0, stream>>>(part, s1, 32);
  finalize_stats<<<1, 256, 0, stream>>>(s1, 64, 1.f/524288.f, g1, b1, sb + 256);
  // layer 2 (in-place, 1-ahead y prefetch)
  gemm4<1><<<NROW/256, 256, 0, stream>>>(nullptr, nullptr, y, sb + 256, WB + 32768, y, part);
  reduce_stage1<<<64, 256, 0, stream>>>(part, s1, 32);
  finalize_stats<<<1, 256, 0, stream>>>(s1, 64, 1.f/524288.f, g2, b2, sb + 512);
  // shortcut
  sc_gemm<<<NROWSC/64, 256, 0, stream>>>(featsT, Wsc, scbuf, part);
  reduce_stage1<<<8, 256, 0, stream>>>(part, s1, 64);
  finalize_stats<<<1, 256, 0, stream>>>(s1, 8, 1.f/32768.f, gsc, bsc, sb + 768);
  // fuse + transpose
  final_kernel<<<512, 256, 0, stream>>>(y, scbuf, sb + 512, sb + 768, out);
}

// Round 18
// 371.728 us; speedup vs baseline: 2.3399x; 1.0130x over previous
//
#include <hip/hip_runtime.h>

// EdgeConvBlock: B=32, N=1024, D=3, CIN=64, K=16, COUT=128x3
// Round 18: fuse independent prologue kernels {transpose_feats, convert_w, knn}
// into one block-range-dispatched prep_kernel (they serialize on the stream but
// have no data deps; knn is latency-bound and hides the other two). Hot kernels
// (gemm4, final) identical to r17's verified best (376.5us).

#define BB 32
#define NN 1024
#define CINC 64
#define KK 16
#define CO 128
#define NROW (BB*NN*KK)   // 524288
#define NROWSC (BB*NN)    // 32768

// ---- ws layout (bytes) ----
static const size_t OFF_FT   = 0;            // featsT f32 [B][N][64]       8,388,608
static const size_t OFF_IDX  = 8388608;      // idx int  [B][N][16]         2,097,152
static const size_t OFF_Y    = 10485760;     // y  bf16  [NROW][128]      134,217,728
static const size_t OFF_SC   = 144703488;    // sc f32   [NROWSC][128]     16,777,216
static const size_t OFF_PART = 161480704;    // partials f32 [2048][256] (2MB used of 8MB)
static const size_t OFF_WB   = 165675008;    // swizzled bf16 W [3][16384]     98,304
static const size_t OFF_S1   = 169869312;    // stage1 f32 [64][256]           65,536
static const size_t OFF_SB   = 169934848;    // scale/bias f32 [4][256]         4,096
static const size_t WS_NEED  = 169938944;

typedef __bf16 bf16x8v __attribute__((ext_vector_type(8)));
typedef float  f32x4v  __attribute__((ext_vector_type(4)));

__device__ __forceinline__ float bl(unsigned u){ return __uint_as_float(u<<16); }
__device__ __forceinline__ float bh(unsigned u){ return __uint_as_float(u & 0xffff0000u); }
__device__ __forceinline__ unsigned short bfr(float x){
  unsigned u = __float_as_uint(x);
  u += 0x7fffu + ((u>>16)&1u);
  return (unsigned short)(u>>16);
}
__device__ __forceinline__ unsigned short b16(float x){
  return __builtin_bit_cast(unsigned short, (__bf16)x);   // HW RNE convert
}

// ---------------- diagnostic sentinel ----------------
__global__ __launch_bounds__(256) void sentinel_kernel(float* __restrict__ out, int n, float v){
  int i = blockIdx.x*256 + threadIdx.x;
  if (i < n) out[i] = v;
}

// ---------------- fused prologue: transpose (512 blk) | convert_w (24 blk) | knn (1024 blk) ----------------
__global__ __launch_bounds__(256) void prep_kernel(const float* __restrict__ f,
                                                   const float* __restrict__ pts,
                                                   const float* __restrict__ W0,
                                                   const float* __restrict__ W1,
                                                   const float* __restrict__ W2,
                                                   float* __restrict__ ft,
                                                   unsigned short* __restrict__ WB,
                                                   int* __restrict__ idxout){
  __shared__ __align__(16) char smem[34816];
  int t = threadIdx.x;
  int bid = blockIdx.x;

  if (bid < 512){
    // ---- transpose features (b,c,n) -> (b,n,c) ----
    float (*tile)[65] = (float(*)[65])smem;     // 16.6KB of 34.8KB
    int b = bid >> 4, n0 = (bid & 15) * 64;
    for (int it=0; it<16; ++it){
      int flat = it*256 + t;
      int c = flat>>6, nl = flat&63;
      tile[c][nl] = f[(b*64 + c)*1024 + n0 + nl];
    }
    __syncthreads();
    for (int it=0; it<16; ++it){
      int flat = it*256 + t;
      int nl = flat>>6, c = flat&63;
      ft[((b<<10) + n0 + nl)*64 + c] = tile[c][nl];
    }
    return;
  }

  if (bid < 536){
    // ---- weight pre-swizzle: WB[lay][(kb*8+cf)*64+l][j] = W[cf*16+(l&15)][kb*32+(l>>4)*8+j] ----
    int tid = (bid - 512)*256 + t;               // 0..6143
    int lay = tid >> 11, rem = tid & 2047;
    int fidx = rem >> 6, l = rem & 63;
    int kb = fidx >> 3, cf = fidx & 7;
    int li = l & 15, lg = l >> 4;
    const float* Ws = lay==0 ? W0 : (lay==1 ? W1 : W2);
    int o = cf*16 + li;
    unsigned short p[8];
    #pragma unroll
    for (int j=0;j<8;++j) p[j] = bfr(Ws[o*128 + kb*32 + lg*8 + j]);
    uint4 o4;
    o4.x = (unsigned)p[0] | ((unsigned)p[1]<<16);
    o4.y = (unsigned)p[2] | ((unsigned)p[3]<<16);
    o4.z = (unsigned)p[4] | ((unsigned)p[5]<<16);
    o4.w = (unsigned)p[6] | ((unsigned)p[7]<<16);
    *reinterpret_cast<uint4*>(WB + (size_t)lay*16384 + (size_t)rem*8) = o4;
    return;
  }

  // ---- KNN v4: packed-key cascade, 32 queries x 8 chunks of 128 ----
  // key = positive normal double: [bit62=1][fkey32(pd)][tie=1023-m] -> f64 order == top_k order.
  {
    int kbid = bid - 536;
    int b = kbid >> 5, g = kbid & 31;
    float4* p4 = (float4*)smem;                          // [1024] during scan
    unsigned long long (*mk)[32][17] =
        (unsigned long long(*)[32][17])smem;             // [8][32][17] keys after scan

    for (int i=t; i<1024; i+=256){
      float a = pts[(b*3+0)*1024+i];
      float c = pts[(b*3+1)*1024+i];
      float d = pts[(b*3+2)*1024+i];
      float xx = __fadd_rn(__fadd_rn(__fmul_rn(a,a), __fmul_rn(c,c)), __fmul_rn(d,d));
      p4[i] = make_float4(a, c, d, xx);
    }
    __syncthreads();

    int q = t & 31, c = t >> 5;       // query-in-block, chunk
    int n = g*32 + q;
    float4 qp = p4[n];
    float qx=qp.x, qy=qp.y, qz=qp.z, qxx=qp.w;
    double vals[16];
    #pragma unroll
    for (int j=0;j<16;++j) vals[j] = 0.0;

    int m0 = c*128;
    for (int i0=0; i0<128; i0+=4){
      float4 cand[4];
      #pragma unroll
      for (int u=0;u<4;++u) cand[u] = p4[m0 + i0 + u];
      #pragma unroll
      for (int u=0;u<4;++u){
        int m = m0 + i0 + u;
        float inner = __fadd_rn(__fadd_rn(__fmul_rn(qx,cand[u].x), __fmul_rn(qy,cand[u].y)), __fmul_rn(qz,cand[u].z));
        float pd = __fsub_rn(__fsub_rn(__fmul_rn(2.0f, inner), qxx), cand[u].w);
        unsigned uv = __float_as_uint(pd);
        unsigned fk = uv ^ (0x80000000u | (unsigned)((int)uv >> 31));  // monotone f32->u32
        unsigned lo = (fk << 20) | (unsigned)(1023 - m);
        unsigned hi = 0x40000000u | (fk >> 12);
        hi = (m == n) ? 0u : hi;                                       // self -> tiny key
        double key = __builtin_bit_cast(double, ((unsigned long long)hi << 32) | lo);
        #pragma unroll
        for (int j=0;j<16;++j){
          double mx = fmax(vals[j], key);
          key = fmin(vals[j], key);
          vals[j] = mx;
        }
      }
    }
    __syncthreads();                    // scans done; points dead -> key lists live
    #pragma unroll
    for (int j=0;j<16;++j) mk[c][q][j] = __builtin_bit_cast(unsigned long long, vals[j]);
    mk[c][q][16] = 0ull;                // sentinel
    __syncthreads();

    if (t < 32){
      int qq = t;
      int p0=0,p1=0,p2=0,p3=0,p4i=0,p5=0,p6=0,p7=0;
      unsigned long long v0=mk[0][qq][0], v1=mk[1][qq][0], v2=mk[2][qq][0], v3=mk[3][qq][0];
      unsigned long long v4=mk[4][qq][0], v5=mk[5][qq][0], v6=mk[6][qq][0], v7=mk[7][qq][0];
      int* dst = idxout + ((size_t)((b<<10) + g*32 + qq))*16;
      #pragma unroll
      for (int j=0;j<16;++j){
        unsigned long long best = v0; int bc = 0;
        if (v1 > best){ best = v1; bc = 1; }
        if (v2 > best){ best = v2; bc = 2; }
        if (v3 > best){ best = v3; bc = 3; }
        if (v4 > best){ best = v4; bc = 4; }
        if (v5 > best){ best = v5; bc = 5; }
        if (v6 > best){ best = v6; bc = 6; }
        if (v7 > best){ best = v7; bc = 7; }
        dst[j] = 1023 - (int)(best & 1023ull);
        if      (bc==0){ ++p0; v0 = mk[0][qq][p0]; }
        else if (bc==1){ ++p1; v1 = mk[1][qq][p1]; }
        else if (bc==2){ ++p2; v2 = mk[2][qq][p2]; }
        else if (bc==3){ ++p3; v3 = mk[3][qq][p3]; }
        else if (bc==4){ ++p4i; v4 = mk[4][qq][p4i]; }
        else if (bc==5){ ++p5; v5 = mk[5][qq][p5]; }
        else if (bc==6){ ++p6; v6 = mk[6][qq][p6]; }
        else           { ++p7; v7 = mk[7][qq][p7]; }
      }
    }
  }
}

// ---------------- GEMM v4 (r12/r15 best): 256x128 per block, K=128, 1-ahead prefetch ----------------
// MODE 0: x = (center || nbr-center); MODE 1: x = relu(yin*s+b), in-place safe.
template<int MODE>
__global__ __launch_bounds__(256, 2) void gemm4(const float* __restrict__ featsT,
                                                const int* __restrict__ knnidx,
                                                const unsigned short* yin,
                                                const float* __restrict__ sb,
                                                const unsigned short* __restrict__ Wswz,
                                                unsigned short* yout,
                                                float* __restrict__ partials){
  __shared__ __align__(16) unsigned short Wl[16384];       // 32KB swizzled W
  __shared__ __align__(16) unsigned short tb[4][16][132];  // 16.9KB per-wave transpose
  float* red = (float*)&tb[0][0][0];                       // 4KB alias (used after barrier)

  int t = threadIdx.x;
  int w = t >> 6, l = t & 63;
  int li = l & 15, lg = l >> 4;

  // stage swizzled W: linear 32KB copy
  #pragma unroll
  for (int it=0; it<8; ++it){
    int v = it*256 + t;
    *reinterpret_cast<uint4*>(&Wl[v*8]) =
      *reinterpret_cast<const uint4*>(Wswz + (size_t)v*8);
  }
  __syncthreads();

  float ss[8] = {0.f,0.f,0.f,0.f,0.f,0.f,0.f,0.f};
  float sq[8] = {0.f,0.f,0.f,0.f,0.f,0.f,0.f,0.f};

  // -------- epilogue (shared by both modes) --------
  auto epilogue = [&](int rg, f32x4v (&acc)[8]){
    size_t rbase = (size_t)blockIdx.x*256 + w*64 + rg*16;
    #pragma unroll
    for (int cf=0; cf<8; ++cf){
      ss[cf] += acc[cf][0]+acc[cf][1]+acc[cf][2]+acc[cf][3];
      sq[cf] += acc[cf][0]*acc[cf][0]+acc[cf][1]*acc[cf][1]+acc[cf][2]*acc[cf][2]+acc[cf][3]*acc[cf][3];
    }
    #pragma unroll
    for (int cf=0; cf<8; ++cf){
      tb[w][lg*4 + 0][cf*16 + li] = b16(acc[cf][0]);
      tb[w][lg*4 + 1][cf*16 + li] = b16(acc[cf][1]);
      tb[w][lg*4 + 2][cf*16 + li] = b16(acc[cf][2]);
      tb[w][lg*4 + 3][cf*16 + li] = b16(acc[cf][3]);
    }
    __builtin_amdgcn_wave_barrier();   // scatter writes before cross-lane reads
    {
      int row4 = l >> 4, ch = l & 15;
      #pragma unroll
      for (int s2=0; s2<4; ++s2){
        const unsigned short* src = &tb[w][s2*4 + row4][ch*8];
        unsigned short* dst = yout + (rbase + s2*4 + row4)*128 + ch*8;
        *reinterpret_cast<uint4*>(dst) = *reinterpret_cast<const uint4*>(src);
      }
    }
    __builtin_amdgcn_wave_barrier();   // reads done before next rg's scatter
  };

  if constexpr (MODE == 1){
    const unsigned short* ybase = yin + ((size_t)blockIdx.x*256 + w*64 + li)*128 + lg*8;
    uint4 yb[2][4];
    #pragma unroll
    for (int kb=0; kb<4; ++kb)
      yb[0][kb] = *reinterpret_cast<const uint4*>(ybase + kb*32);
    #pragma unroll
    for (int rg=0; rg<4; ++rg){
      if (rg < 3){   // 1-ahead prefetch (issued before any compute/barrier of this rg)
        #pragma unroll
        for (int kb=0; kb<4; ++kb)
          yb[(rg+1)&1][kb] = *reinterpret_cast<const uint4*>(ybase + (size_t)(rg+1)*2048 + kb*32);
      }
      f32x4v acc[8] = {};
      #pragma unroll
      for (int kb=0; kb<4; ++kb){
        int c0 = kb*32 + lg*8;
        uint4 yv = yb[rg&1][kb];
        float4 s0 = *reinterpret_cast<const float4*>(sb + c0);
        float4 s1 = *reinterpret_cast<const float4*>(sb + c0 + 4);
        float4 b0 = *reinterpret_cast<const float4*>(sb + 128 + c0);
        float4 b1 = *reinterpret_cast<const float4*>(sb + 128 + c0 + 4);
        bf16x8v av;
        av[0] = (__bf16)fmaxf(fmaf(bl(yv.x), s0.x, b0.x), 0.f);
        av[1] = (__bf16)fmaxf(fmaf(bh(yv.x), s0.y, b0.y), 0.f);
        av[2] = (__bf16)fmaxf(fmaf(bl(yv.y), s0.z, b0.z), 0.f);
        av[3] = (__bf16)fmaxf(fmaf(bh(yv.y), s0.w, b0.w), 0.f);
        av[4] = (__bf16)fmaxf(fmaf(bl(yv.z), s1.x, b1.x), 0.f);
        av[5] = (__bf16)fmaxf(fmaf(bh(yv.z), s1.y, b1.y), 0.f);
        av[6] = (__bf16)fmaxf(fmaf(bl(yv.w), s1.z, b1.z), 0.f);
        av[7] = (__bf16)fmaxf(fmaf(bh(yv.w), s1.w, b1.w), 0.f);
        #pragma unroll
        for (int cf=0; cf<8; ++cf){
          uint4 b4 = *reinterpret_cast<const uint4*>(&Wl[((kb*8+cf)*64 + l)*8]);
          acc[cf] = __builtin_amdgcn_mfma_f32_16x16x32_bf16(av, __builtin_bit_cast(bf16x8v, b4), acc[cf], 0, 0, 0);
        }
      }
      epilogue(rg, acc);
    }
  } else {
    int b = blockIdx.x >> 6;                     // 64 blocks per batch
    int nbase = (blockIdx.x & 63)*16 + w*4;      // point n for rg = nbase + rg
    const float* fb = featsT + (((size_t)b)<<10)*64;
    int nbr[4];
    #pragma unroll
    for (int rg=0; rg<4; ++rg)
      nbr[rg] = knnidx[((size_t)((b<<10) + nbase + rg))*16 + li];
    float4 cg[2][4], ng[2][4];
    {
      const float* cp = fb + (size_t)nbase*64 + lg*8;
      const float* np = fb + (size_t)nbr[0]*64 + lg*8;
      cg[0][0] = *reinterpret_cast<const float4*>(cp);
      cg[0][1] = *reinterpret_cast<const float4*>(cp + 4);
      cg[0][2] = *reinterpret_cast<const float4*>(cp + 32);
      cg[0][3] = *reinterpret_cast<const float4*>(cp + 36);
      ng[0][0] = *reinterpret_cast<const float4*>(np);
      ng[0][1] = *reinterpret_cast<const float4*>(np + 4);
      ng[0][2] = *reinterpret_cast<const float4*>(np + 32);
      ng[0][3] = *reinterpret_cast<const float4*>(np + 36);
    }
    #pragma unroll
    for (int rg=0; rg<4; ++rg){
      if (rg < 3){   // prefetch next rg's gather
        const float* cp = fb + (size_t)(nbase + rg + 1)*64 + lg*8;
        const float* np = fb + (size_t)nbr[rg+1]*64 + lg*8;
        cg[(rg+1)&1][0] = *reinterpret_cast<const float4*>(cp);
        cg[(rg+1)&1][1] = *reinterpret_cast<const float4*>(cp + 4);
        cg[(rg+1)&1][2] = *reinterpret_cast<const float4*>(cp + 32);
        cg[(rg+1)&1][3] = *reinterpret_cast<const float4*>(cp + 36);
        ng[(rg+1)&1][0] = *reinterpret_cast<const float4*>(np);
        ng[(rg+1)&1][1] = *reinterpret_cast<const float4*>(np + 4);
        ng[(rg+1)&1][2] = *reinterpret_cast<const float4*>(np + 32);
        ng[(rg+1)&1][3] = *reinterpret_cast<const float4*>(np + 36);
      }
      float4 cl0 = cg[rg&1][0], cl1 = cg[rg&1][1], ch0 = cg[rg&1][2], ch1 = cg[rg&1][3];
      float4 nl0 = ng[rg&1][0], nl1 = ng[rg&1][1], nh0 = ng[rg&1][2], nh1 = ng[rg&1][3];
      bf16x8v afr[4];
      afr[0][0]=(__bf16)cl0.x; afr[0][1]=(__bf16)cl0.y; afr[0][2]=(__bf16)cl0.z; afr[0][3]=(__bf16)cl0.w;
      afr[0][4]=(__bf16)cl1.x; afr[0][5]=(__bf16)cl1.y; afr[0][6]=(__bf16)cl1.z; afr[0][7]=(__bf16)cl1.w;
      afr[1][0]=(__bf16)ch0.x; afr[1][1]=(__bf16)ch0.y; afr[1][2]=(__bf16)ch0.z; afr[1][3]=(__bf16)ch0.w;
      afr[1][4]=(__bf16)ch1.x; afr[1][5]=(__bf16)ch1.y; afr[1][6]=(__bf16)ch1.z; afr[1][7]=(__bf16)ch1.w;
      afr[2][0]=(__bf16)(nl0.x-cl0.x); afr[2][1]=(__bf16)(nl0.y-cl0.y);
      afr[2][2]=(__bf16)(nl0.z-cl0.z); afr[2][3]=(__bf16)(nl0.w-cl0.w);
      afr[2][4]=(__bf16)(nl1.x-cl1.x); afr[2][5]=(__bf16)(nl1.y-cl1.y);
      afr[2][6]=(__bf16)(nl1.z-cl1.z); afr[2][7]=(__bf16)(nl1.w-cl1.w);
      afr[3][0]=(__bf16)(nh0.x-ch0.x); afr[3][1]=(__bf16)(nh0.y-ch0.y);
      afr[3][2]=(__bf16)(nh0.z-ch0.z); afr[3][3]=(__bf16)(nh0.w-ch0.w);
      afr[3][4]=(__bf16)(nh1.x-ch1.x); afr[3][5]=(__bf16)(nh1.y-ch1.y);
      afr[3][6]=(__bf16)(nh1.z-ch1.z); afr[3][7]=(__bf16)(nh1.w-ch1.w);
      f32x4v acc[8] = {};
      #pragma unroll
      for (int kb=0; kb<4; ++kb){
        #pragma unroll
        for (int cf=0; cf<8; ++cf){
          uint4 b4 = *reinterpret_cast<const uint4*>(&Wl[((kb*8+cf)*64 + l)*8]);
          acc[cf] = __builtin_amdgcn_mfma_f32_16x16x32_bf16(afr[kb], __builtin_bit_cast(bf16x8v, b4), acc[cf], 0, 0, 0);
        }
      }
      epilogue(rg, acc);
    }
  }

  // ---- cross-wave stats (red aliases tb; barrier first) ----
  __syncthreads();
  #pragma unroll
  for (int cf=0; cf<8; ++cf){
    float s = ss[cf];
    s += __shfl_xor(s, 16);
    s += __shfl_xor(s, 32);
    float q = sq[cf];
    q += __shfl_xor(q, 16);
    q += __shfl_xor(q, 32);
    if (lg == 0){
      red[w*128 + cf*16 + li]       = s;
      red[512 + w*128 + cf*16 + li] = q;
    }
  }
  __syncthreads();
  {
    int col = t & 127;
    int base = (t >> 7) * 512;
    float s = red[base + col] + red[base + 128 + col] + red[base + 256 + col] + red[base + 384 + col];
    partials[(size_t)blockIdx.x*256 + (t>>7)*128 + col] = s;
  }
}

// ---------------- shortcut GEMM: feats(64) x Wsc^T -> sc f32 ----------------
__global__ __launch_bounds__(256) void sc_gemm(const float* __restrict__ featsT,
                                               const float* __restrict__ W,
                                               float* __restrict__ scout,
                                               float* __restrict__ partials){
  __shared__ __align__(16) unsigned short Wt[64][136];
  __shared__ __align__(16) unsigned short xs[64][72];
  int t = threadIdx.x, tx = t&15, ty = t>>4;
  int rowbase = blockIdx.x * 64;
  for (int it=0; it<32; ++it){
    int flat = it*256 + t;
    int o = flat>>6, c = flat&63;
    Wt[c][o] = bfr(W[flat]);
  }
  for (int it=0; it<16; ++it){
    int flat = it*256 + t;
    int r = flat>>6, c = flat&63;
    xs[r][c] = bfr(featsT[(size_t)(rowbase + r)*64 + c]);
  }
  __syncthreads();
  float acc[4][8] = {};
  for (int c=0;c<64;++c){
    uint4 wv = *reinterpret_cast<const uint4*>(&Wt[c][tx*8]);
    float w[8];
    w[0]=bl(wv.x); w[1]=bh(wv.x); w[2]=bl(wv.y); w[3]=bh(wv.y);
    w[4]=bl(wv.z); w[5]=bh(wv.z); w[6]=bl(wv.w); w[7]=bh(wv.w);
    #pragma unroll
    for (int i=0;i<4;++i){
      float xv = bl((unsigned)xs[ty*4+i][c]);
      #pragma unroll
      for (int j=0;j<8;++j) acc[i][j] = fmaf(xv, w[j], acc[i][j]);
    }
  }
  #pragma unroll
  for (int i=0;i<4;++i)
    #pragma unroll
    for (int j=0;j<8;++j)
      scout[(size_t)(rowbase + ty*4 + i)*128 + tx*8 + j] = acc[i][j];

  __syncthreads();
  float* red = reinterpret_cast<float*>(&xs[0][0]);
  #pragma unroll
  for (int j=0;j<8;++j){
    float s=0.f;
    #pragma unroll
    for (int i=0;i<4;++i) s += acc[i][j];
    red[ty*128 + tx*8 + j] = s;
  }
  __syncthreads();
  if (t<128){
    float s=0.f;
    for (int y2=0;y2<16;++y2) s += red[y2*128 + t];
    partials[(size_t)blockIdx.x*256 + t] = s;
  }
  __syncthreads();
  #pragma unroll
  for (int j=0;j<8;++j){
    float s=0.f;
    #pragma unroll
    for (int i=0;i<4;++i) s += acc[i][j]*acc[i][j];
    red[ty*128 + tx*8 + j] = s;
  }
  __syncthreads();
  if (t<128){
    float s=0.f;
    for (int y2=0;y2<16;++y2) s += red[y2*128 + t];
    partials[(size_t)blockIdx.x*256 + 128 + t] = s;
  }
}

// ---------------- deterministic stat reduction ----------------
__global__ __launch_bounds__(256) void reduce_stage1(const float* __restrict__ partials,
                                                     float* __restrict__ out, int rows){
  int t = threadIdx.x;
  size_t base = (size_t)blockIdx.x * rows * 256;
  float acc = 0.f;
  for (int r=0;r<rows;++r) acc += partials[base + (size_t)r*256 + t];
  out[blockIdx.x*256 + t] = acc;
}

__global__ __launch_bounds__(256) void finalize_stats(const float* __restrict__ s1, int g1,
                                                      float inv_count,
                                                      const float* __restrict__ g,
                                                      const float* __restrict__ beta,
                                                      float* __restrict__ sb){
  int t = threadIdx.x;
  float acc = 0.f;
  for (int j=0;j<g1;++j) acc += s1[j*256 + t];
  __shared__ float tot[256];
  tot[t] = acc;
  __syncthreads();
  if (t < 128){
    float mean = tot[t] * inv_count;
    float var  = tot[128+t] * inv_count - mean*mean;
    var = fmaxf(var, 0.f);
    float rstd = 1.0f / sqrtf(var + 1e-5f);
    float s = g[t] * rstd;
    sb[t] = s;
    sb[128+t] = beta[t] - mean*s;
  }
}

// ---------------- final v2: vectorized y2 loads (uint4) ----------------
__global__ __launch_bounds__(256) void final_kernel(const unsigned short* __restrict__ y2,
                                                    const float* __restrict__ sc,
                                                    const float* __restrict__ sb2,
                                                    const float* __restrict__ sbsc,
                                                    float* __restrict__ out){
  __shared__ __align__(16) float obuf[64][130];
  int t = threadIdx.x;
  int b = blockIdx.x >> 4;
  int n0 = (blockIdx.x & 15) * 64;
  int oc = (t & 15) * 8;     // 8 consecutive channels per thread
  int nl0 = t >> 4;          // 16 rows per pass, 4 passes

  float4 s2a = *reinterpret_cast<const float4*>(sb2 + oc);
  float4 s2b = *reinterpret_cast<const float4*>(sb2 + oc + 4);
  float4 c2a = *reinterpret_cast<const float4*>(sb2 + 128 + oc);
  float4 c2b = *reinterpret_cast<const float4*>(sb2 + 128 + oc + 4);
  float4 ssa = *reinterpret_cast<const float4*>(sbsc + oc);
  float4 ssb = *reinterpret_cast<const float4*>(sbsc + oc + 4);
  float4 csa = *reinterpret_cast<const float4*>(sbsc + 128 + oc);
  float4 csb = *reinterpret_cast<const float4*>(sbsc + 128 + oc + 4);

  #pragma unroll
  for (int p=0; p<4; ++p){
    int nl = p*16 + nl0;
    size_t nglob = (size_t)((b<<10) + n0 + nl);
    const unsigned short* yp = y2 + (nglob<<4)*128 + oc;
    float a0=0,a1=0,a2=0,a3=0,a4=0,a5=0,a6=0,a7=0;
    #pragma unroll
    for (int k=0;k<16;++k){
      uint4 v = *reinterpret_cast<const uint4*>(yp + k*128);
      a0 += fmaxf(fmaf(bl(v.x), s2a.x, c2a.x), 0.f);
      a1 += fmaxf(fmaf(bh(v.x), s2a.y, c2a.y), 0.f);
      a2 += fmaxf(fmaf(bl(v.y), s2a.z, c2a.z), 0.f);
      a3 += fmaxf(fmaf(bh(v.y), s2a.w, c2a.w), 0.f);
      a4 += fmaxf(fmaf(bl(v.z), s2b.x, c2b.x), 0.f);
      a5 += fmaxf(fmaf(bh(v.z), s2b.y, c2b.y), 0.f);
      a6 += fmaxf(fmaf(bl(v.w), s2b.z, c2b.z), 0.f);
      a7 += fmaxf(fmaf(bh(v.w), s2b.w, c2b.w), 0.f);
    }
    const float* scp = sc + nglob*128 + oc;
    float4 v0 = *reinterpret_cast<const float4*>(scp);
    float4 v1 = *reinterpret_cast<const float4*>(scp + 4);
    float4 o0, o1;
    o0.x = fmaxf(fmaf(v0.x, ssa.x, csa.x) + a0*(1.f/16.f), 0.f);
    o0.y = fmaxf(fmaf(v0.y, ssa.y, csa.y) + a1*(1.f/16.f), 0.f);
    o0.z = fmaxf(fmaf(v0.z, ssa.z, csa.z) + a2*(1.f/16.f), 0.f);
    o0.w = fmaxf(fmaf(v0.w, ssa.w, csa.w) + a3*(1.f/16.f), 0.f);
    o1.x = fmaxf(fmaf(v1.x, ssb.x, csb.x) + a4*(1.f/16.f), 0.f);
    o1.y = fmaxf(fmaf(v1.y, ssb.y, csb.y) + a5*(1.f/16.f), 0.f);
    o1.z = fmaxf(fmaf(v1.z, ssb.z, csb.z) + a6*(1.f/16.f), 0.f);
    o1.w = fmaxf(fmaf(v1.w, ssb.w, csb.w) + a7*(1.f/16.f), 0.f);
    *reinterpret_cast<float4*>(&obuf[nl][oc])     = o0;
    *reinterpret_cast<float4*>(&obuf[nl][oc + 4]) = o1;
  }
  __syncthreads();
  for (int it=0; it<32; ++it){
    int flat = it*256 + t;
    int oo = flat>>6, nl = flat&63;
    out[((size_t)b<<17) + (oo<<10) + n0 + nl] = obuf[nl][oo];
  }
}

extern "C" void kernel_launch(void* const* d_in, const int* in_sizes, int n_in,
                              void* d_out, int out_size, void* d_ws, size_t ws_size,
                              hipStream_t stream) {
  const float* points   = (const float*)d_in[0];
  const float* features = (const float*)d_in[1];
  const float* W0  = (const float*)d_in[2];
  const float* g0  = (const float*)d_in[3];
  const float* b0  = (const float*)d_in[4];
  const float* W1  = (const float*)d_in[5];
  const float* g1  = (const float*)d_in[6];
  const float* b1  = (const float*)d_in[7];
  const float* W2  = (const float*)d_in[8];
  const float* g2  = (const float*)d_in[9];
  const float* b2  = (const float*)d_in[10];
  const float* Wsc = (const float*)d_in[11];
  const float* gsc = (const float*)d_in[12];
  const float* bsc = (const float*)d_in[13];

  float* out = (float*)d_out;

  if (ws_size < WS_NEED){
    float v = (float)(ws_size >> 20);
    sentinel_kernel<<<(out_size + 255)/256, 256, 0, stream>>>(out, out_size, v);
    return;
  }

  char* ws = (char*)d_ws;
  float*          featsT = (float*)(ws + OFF_FT);
  int*            idx    = (int*)(ws + OFF_IDX);
  unsigned short* y      = (unsigned short*)(ws + OFF_Y);
  float*          scbuf  = (float*)(ws + OFF_SC);
  float*          part   = (float*)(ws + OFF_PART);
  unsigned short* WB     = (unsigned short*)(ws + OFF_WB);
  float*          s1     = (float*)(ws + OFF_S1);
  float*          sb     = (float*)(ws + OFF_SB);

  // fused prologue: transpose (512) | convert_w (24) | knn (1024)
  prep_kernel<<<1560, 256, 0, stream>>>(features, points, W0, W1, W2, featsT, WB, idx);

  // layer 0 (gather + MFMA, W in LDS pre-swizzled, pipelined gather)
  gemm4<0><<<NROW/256, 256, 0, stream>>>(featsT, idx, nullptr, nullptr, WB, y, part);
  reduce_stage1<<<64, 256, 0, stream>>>(part, s1, 32);
  finalize_stats<<<1, 256, 0, stream>>>(s1, 64, 1.f/524288.f, g0, b0, sb + 0);
  // layer 1 (in-place, 1-ahead y prefetch)
  gemm4<1><<<NROW/256, 256, 0, stream>>>(nullptr, nullptr, y, sb + 0, WB + 16384, y, part);
  reduce_stage1<<<64, 256, 0, stream>>>(part, s1, 32);
  finalize_stats<<<1, 256, 0, stream>>>(s1, 64, 1.f/524288.f, g1, b1, sb + 256);
  // layer 2 (in-place, 1-ahead y prefetch)
  gemm4<1><<<NROW/256, 256, 0, stream>>>(nullptr, nullptr, y, sb + 256, WB + 32768, y, part);
  reduce_stage1<<<64, 256, 0, stream>>>(part, s1, 32);
  finalize_stats<<<1, 256, 0, stream>>>(s1, 64, 1.f/524288.f, g2, b2, sb + 512);
  // shortcut
  sc_gemm<<<NROWSC/64, 256, 0, stream>>>(featsT, Wsc, scbuf, part);
  reduce_stage1<<<8, 256, 0, stream>>>(part, s1, 64);
  finalize_stats<<<1, 256, 0, stream>>>(s1, 8, 1.f/32768.f, gsc, bsc, sb + 768);
  // fuse + transpose
  final_kernel<<<512, 256, 0, stream>>>(y, scbuf, sb + 512, sb + 768, out);
}

// Round 19
// 305.386 us; speedup vs baseline: 2.8482x; 1.2172x over previous
//
#include <hip/hip_runtime.h>

// EdgeConvBlock: B=32, N=1024, D=3, CIN=64, K=16, COUT=128x3
// Round 19: fuse reduce_stage1+finalize_stats -> bn_stats (one block per channel,
// strided column sums + LDS tree). 8 stat dispatches -> 4. Hot kernels identical
// to r18's verified best (371.7us).

#define BB 32
#define NN 1024
#define CINC 64
#define KK 16
#define CO 128
#define NROW (BB*NN*KK)   // 524288
#define NROWSC (BB*NN)    // 32768

// ---- ws layout (bytes) ----
static const size_t OFF_FT   = 0;            // featsT f32 [B][N][64]       8,388,608
static const size_t OFF_IDX  = 8388608;      // idx int  [B][N][16]         2,097,152
static const size_t OFF_Y    = 10485760;     // y  bf16  [NROW][128]      134,217,728
static const size_t OFF_SC   = 144703488;    // sc f32   [NROWSC][128]     16,777,216
static const size_t OFF_PART = 161480704;    // partials f32 [2048][256] (2MB used of 8MB)
static const size_t OFF_WB   = 165675008;    // swizzled bf16 W [3][16384]     98,304
static const size_t OFF_S1   = 169869312;    // (unused)                       65,536
static const size_t OFF_SB   = 169934848;    // scale/bias f32 [4][256]         4,096
static const size_t WS_NEED  = 169938944;

typedef __bf16 bf16x8v __attribute__((ext_vector_type(8)));
typedef float  f32x4v  __attribute__((ext_vector_type(4)));

__device__ __forceinline__ float bl(unsigned u){ return __uint_as_float(u<<16); }
__device__ __forceinline__ float bh(unsigned u){ return __uint_as_float(u & 0xffff0000u); }
__device__ __forceinline__ unsigned short bfr(float x){
  unsigned u = __float_as_uint(x);
  u += 0x7fffu + ((u>>16)&1u);
  return (unsigned short)(u>>16);
}
__device__ __forceinline__ unsigned short b16(float x){
  return __builtin_bit_cast(unsigned short, (__bf16)x);   // HW RNE convert
}

// ---------------- diagnostic sentinel ----------------
__global__ __launch_bounds__(256) void sentinel_kernel(float* __restrict__ out, int n, float v){
  int i = blockIdx.x*256 + threadIdx.x;
  if (i < n) out[i] = v;
}

// ---------------- fused prologue: transpose (512 blk) | convert_w (24 blk) | knn (1024 blk) ----------------
__global__ __launch_bounds__(256) void prep_kernel(const float* __restrict__ f,
                                                   const float* __restrict__ pts,
                                                   const float* __restrict__ W0,
                                                   const float* __restrict__ W1,
                                                   const float* __restrict__ W2,
                                                   float* __restrict__ ft,
                                                   unsigned short* __restrict__ WB,
                                                   int* __restrict__ idxout){
  __shared__ __align__(16) char smem[34816];
  int t = threadIdx.x;
  int bid = blockIdx.x;

  if (bid < 512){
    // ---- transpose features (b,c,n) -> (b,n,c) ----
    float (*tile)[65] = (float(*)[65])smem;     // 16.6KB of 34.8KB
    int b = bid >> 4, n0 = (bid & 15) * 64;
    for (int it=0; it<16; ++it){
      int flat = it*256 + t;
      int c = flat>>6, nl = flat&63;
      tile[c][nl] = f[(b*64 + c)*1024 + n0 + nl];
    }
    __syncthreads();
    for (int it=0; it<16; ++it){
      int flat = it*256 + t;
      int nl = flat>>6, c = flat&63;
      ft[((b<<10) + n0 + nl)*64 + c] = tile[c][nl];
    }
    return;
  }

  if (bid < 536){
    // ---- weight pre-swizzle: WB[lay][(kb*8+cf)*64+l][j] = W[cf*16+(l&15)][kb*32+(l>>4)*8+j] ----
    int tid = (bid - 512)*256 + t;               // 0..6143
    int lay = tid >> 11, rem = tid & 2047;
    int fidx = rem >> 6, l = rem & 63;
    int kb = fidx >> 3, cf = fidx & 7;
    int li = l & 15, lg = l >> 4;
    const float* Ws = lay==0 ? W0 : (lay==1 ? W1 : W2);
    int o = cf*16 + li;
    unsigned short p[8];
    #pragma unroll
    for (int j=0;j<8;++j) p[j] = bfr(Ws[o*128 + kb*32 + lg*8 + j]);
    uint4 o4;
    o4.x = (unsigned)p[0] | ((unsigned)p[1]<<16);
    o4.y = (unsigned)p[2] | ((unsigned)p[3]<<16);
    o4.z = (unsigned)p[4] | ((unsigned)p[5]<<16);
    o4.w = (unsigned)p[6] | ((unsigned)p[7]<<16);
    *reinterpret_cast<uint4*>(WB + (size_t)lay*16384 + (size_t)rem*8) = o4;
    return;
  }

  // ---- KNN v4: packed-key cascade, 32 queries x 8 chunks of 128 ----
  {
    int kbid = bid - 536;
    int b = kbid >> 5, g = kbid & 31;
    float4* p4 = (float4*)smem;                          // [1024] during scan
    unsigned long long (*mk)[32][17] =
        (unsigned long long(*)[32][17])smem;             // [8][32][17] keys after scan

    for (int i=t; i<1024; i+=256){
      float a = pts[(b*3+0)*1024+i];
      float c = pts[(b*3+1)*1024+i];
      float d = pts[(b*3+2)*1024+i];
      float xx = __fadd_rn(__fadd_rn(__fmul_rn(a,a), __fmul_rn(c,c)), __fmul_rn(d,d));
      p4[i] = make_float4(a, c, d, xx);
    }
    __syncthreads();

    int q = t & 31, c = t >> 5;       // query-in-block, chunk
    int n = g*32 + q;
    float4 qp = p4[n];
    float qx=qp.x, qy=qp.y, qz=qp.z, qxx=qp.w;
    double vals[16];
    #pragma unroll
    for (int j=0;j<16;++j) vals[j] = 0.0;

    int m0 = c*128;
    for (int i0=0; i0<128; i0+=4){
      float4 cand[4];
      #pragma unroll
      for (int u=0;u<4;++u) cand[u] = p4[m0 + i0 + u];
      #pragma unroll
      for (int u=0;u<4;++u){
        int m = m0 + i0 + u;
        float inner = __fadd_rn(__fadd_rn(__fmul_rn(qx,cand[u].x), __fmul_rn(qy,cand[u].y)), __fmul_rn(qz,cand[u].z));
        float pd = __fsub_rn(__fsub_rn(__fmul_rn(2.0f, inner), qxx), cand[u].w);
        unsigned uv = __float_as_uint(pd);
        unsigned fk = uv ^ (0x80000000u | (unsigned)((int)uv >> 31));  // monotone f32->u32
        unsigned lo = (fk << 20) | (unsigned)(1023 - m);
        unsigned hi = 0x40000000u | (fk >> 12);
        hi = (m == n) ? 0u : hi;                                       // self -> tiny key
        double key = __builtin_bit_cast(double, ((unsigned long long)hi << 32) | lo);
        #pragma unroll
        for (int j=0;j<16;++j){
          double mx = fmax(vals[j], key);
          key = fmin(vals[j], key);
          vals[j] = mx;
        }
      }
    }
    __syncthreads();                    // scans done; points dead -> key lists live
    #pragma unroll
    for (int j=0;j<16;++j) mk[c][q][j] = __builtin_bit_cast(unsigned long long, vals[j]);
    mk[c][q][16] = 0ull;                // sentinel
    __syncthreads();

    if (t < 32){
      int qq = t;
      int p0=0,p1=0,p2=0,p3=0,p4i=0,p5=0,p6=0,p7=0;
      unsigned long long v0=mk[0][qq][0], v1=mk[1][qq][0], v2=mk[2][qq][0], v3=mk[3][qq][0];
      unsigned long long v4=mk[4][qq][0], v5=mk[5][qq][0], v6=mk[6][qq][0], v7=mk[7][qq][0];
      int* dst = idxout + ((size_t)((b<<10) + g*32 + qq))*16;
      #pragma unroll
      for (int j=0;j<16;++j){
        unsigned long long best = v0; int bc = 0;
        if (v1 > best){ best = v1; bc = 1; }
        if (v2 > best){ best = v2; bc = 2; }
        if (v3 > best){ best = v3; bc = 3; }
        if (v4 > best){ best = v4; bc = 4; }
        if (v5 > best){ best = v5; bc = 5; }
        if (v6 > best){ best = v6; bc = 6; }
        if (v7 > best){ best = v7; bc = 7; }
        dst[j] = 1023 - (int)(best & 1023ull);
        if      (bc==0){ ++p0; v0 = mk[0][qq][p0]; }
        else if (bc==1){ ++p1; v1 = mk[1][qq][p1]; }
        else if (bc==2){ ++p2; v2 = mk[2][qq][p2]; }
        else if (bc==3){ ++p3; v3 = mk[3][qq][p3]; }
        else if (bc==4){ ++p4i; v4 = mk[4][qq][p4i]; }
        else if (bc==5){ ++p5; v5 = mk[5][qq][p5]; }
        else if (bc==6){ ++p6; v6 = mk[6][qq][p6]; }
        else           { ++p7; v7 = mk[7][qq][p7]; }
      }
    }
  }
}

// ---------------- GEMM v4 (r12/r15 best): 256x128 per block, K=128, 1-ahead prefetch ----------------
// MODE 0: x = (center || nbr-center); MODE 1: x = relu(yin*s+b), in-place safe.
template<int MODE>
__global__ __launch_bounds__(256, 2) void gemm4(const float* __restrict__ featsT,
                                                const int* __restrict__ knnidx,
                                                const unsigned short* yin,
                                                const float* __restrict__ sb,
                                                const unsigned short* __restrict__ Wswz,
                                                unsigned short* yout,
                                                float* __restrict__ partials){
  __shared__ __align__(16) unsigned short Wl[16384];       // 32KB swizzled W
  __shared__ __align__(16) unsigned short tb[4][16][132];  // 16.9KB per-wave transpose
  float* red = (float*)&tb[0][0][0];                       // 4KB alias (used after barrier)

  int t = threadIdx.x;
  int w = t >> 6, l = t & 63;
  int li = l & 15, lg = l >> 4;

  // stage swizzled W: linear 32KB copy
  #pragma unroll
  for (int it=0; it<8; ++it){
    int v = it*256 + t;
    *reinterpret_cast<uint4*>(&Wl[v*8]) =
      *reinterpret_cast<const uint4*>(Wswz + (size_t)v*8);
  }
  __syncthreads();

  float ss[8] = {0.f,0.f,0.f,0.f,0.f,0.f,0.f,0.f};
  float sq[8] = {0.f,0.f,0.f,0.f,0.f,0.f,0.f,0.f};

  // -------- epilogue (shared by both modes) --------
  auto epilogue = [&](int rg, f32x4v (&acc)[8]){
    size_t rbase = (size_t)blockIdx.x*256 + w*64 + rg*16;
    #pragma unroll
    for (int cf=0; cf<8; ++cf){
      ss[cf] += acc[cf][0]+acc[cf][1]+acc[cf][2]+acc[cf][3];
      sq[cf] += acc[cf][0]*acc[cf][0]+acc[cf][1]*acc[cf][1]+acc[cf][2]*acc[cf][2]+acc[cf][3]*acc[cf][3];
    }
    #pragma unroll
    for (int cf=0; cf<8; ++cf){
      tb[w][lg*4 + 0][cf*16 + li] = b16(acc[cf][0]);
      tb[w][lg*4 + 1][cf*16 + li] = b16(acc[cf][1]);
      tb[w][lg*4 + 2][cf*16 + li] = b16(acc[cf][2]);
      tb[w][lg*4 + 3][cf*16 + li] = b16(acc[cf][3]);
    }
    __builtin_amdgcn_wave_barrier();   // scatter writes before cross-lane reads
    {
      int row4 = l >> 4, ch = l & 15;
      #pragma unroll
      for (int s2=0; s2<4; ++s2){
        const unsigned short* src = &tb[w][s2*4 + row4][ch*8];
        unsigned short* dst = yout + (rbase + s2*4 + row4)*128 + ch*8;
        *reinterpret_cast<uint4*>(dst) = *reinterpret_cast<const uint4*>(src);
      }
    }
    __builtin_amdgcn_wave_barrier();   // reads done before next rg's scatter
  };

  if constexpr (MODE == 1){
    const unsigned short* ybase = yin + ((size_t)blockIdx.x*256 + w*64 + li)*128 + lg*8;
    uint4 yb[2][4];
    #pragma unroll
    for (int kb=0; kb<4; ++kb)
      yb[0][kb] = *reinterpret_cast<const uint4*>(ybase + kb*32);
    #pragma unroll
    for (int rg=0; rg<4; ++rg){
      if (rg < 3){   // 1-ahead prefetch (issued before any compute/barrier of this rg)
        #pragma unroll
        for (int kb=0; kb<4; ++kb)
          yb[(rg+1)&1][kb] = *reinterpret_cast<const uint4*>(ybase + (size_t)(rg+1)*2048 + kb*32);
      }
      f32x4v acc[8] = {};
      #pragma unroll
      for (int kb=0; kb<4; ++kb){
        int c0 = kb*32 + lg*8;
        uint4 yv = yb[rg&1][kb];
        float4 s0 = *reinterpret_cast<const float4*>(sb + c0);
        float4 s1 = *reinterpret_cast<const float4*>(sb + c0 + 4);
        float4 b0 = *reinterpret_cast<const float4*>(sb + 128 + c0);
        float4 b1 = *reinterpret_cast<const float4*>(sb + 128 + c0 + 4);
        bf16x8v av;
        av[0] = (__bf16)fmaxf(fmaf(bl(yv.x), s0.x, b0.x), 0.f);
        av[1] = (__bf16)fmaxf(fmaf(bh(yv.x), s0.y, b0.y), 0.f);
        av[2] = (__bf16)fmaxf(fmaf(bl(yv.y), s0.z, b0.z), 0.f);
        av[3] = (__bf16)fmaxf(fmaf(bh(yv.y), s0.w, b0.w), 0.f);
        av[4] = (__bf16)fmaxf(fmaf(bl(yv.z), s1.x, b1.x), 0.f);
        av[5] = (__bf16)fmaxf(fmaf(bh(yv.z), s1.y, b1.y), 0.f);
        av[6] = (__bf16)fmaxf(fmaf(bl(yv.w), s1.z, b1.z), 0.f);
        av[7] = (__bf16)fmaxf(fmaf(bh(yv.w), s1.w, b1.w), 0.f);
        #pragma unroll
        for (int cf=0; cf<8; ++cf){
          uint4 b4 = *reinterpret_cast<const uint4*>(&Wl[((kb*8+cf)*64 + l)*8]);
          acc[cf] = __builtin_amdgcn_mfma_f32_16x16x32_bf16(av, __builtin_bit_cast(bf16x8v, b4), acc[cf], 0, 0, 0);
        }
      }
      epilogue(rg, acc);
    }
  } else {
    int b = blockIdx.x >> 6;                     // 64 blocks per batch
    int nbase = (blockIdx.x & 63)*16 + w*4;      // point n for rg = nbase + rg
    const float* fb = featsT + (((size_t)b)<<10)*64;
    int nbr[4];
    #pragma unroll
    for (int rg=0; rg<4; ++rg)
      nbr[rg] = knnidx[((size_t)((b<<10) + nbase + rg))*16 + li];
    float4 cg[2][4], ng[2][4];
    {
      const float* cp = fb + (size_t)nbase*64 + lg*8;
      const float* np = fb + (size_t)nbr[0]*64 + lg*8;
      cg[0][0] = *reinterpret_cast<const float4*>(cp);
      cg[0][1] = *reinterpret_cast<const float4*>(cp + 4);
      cg[0][2] = *reinterpret_cast<const float4*>(cp + 32);
      cg[0][3] = *reinterpret_cast<const float4*>(cp + 36);
      ng[0][0] = *reinterpret_cast<const float4*>(np);
      ng[0][1] = *reinterpret_cast<const float4*>(np + 4);
      ng[0][2] = *reinterpret_cast<const float4*>(np + 32);
      ng[0][3] = *reinterpret_cast<const float4*>(np + 36);
    }
    #pragma unroll
    for (int rg=0; rg<4; ++rg){
      if (rg < 3){   // prefetch next rg's gather
        const float* cp = fb + (size_t)(nbase + rg + 1)*64 + lg*8;
        const float* np = fb + (size_t)nbr[rg+1]*64 + lg*8;
        cg[(rg+1)&1][0] = *reinterpret_cast<const float4*>(cp);
        cg[(rg+1)&1][1] = *reinterpret_cast<const float4*>(cp + 4);
        cg[(rg+1)&1][2] = *reinterpret_cast<const float4*>(cp + 32);
        cg[(rg+1)&1][3] = *reinterpret_cast<const float4*>(cp + 36);
        ng[(rg+1)&1][0] = *reinterpret_cast<const float4*>(np);
        ng[(rg+1)&1][1] = *reinterpret_cast<const float4*>(np + 4);
        ng[(rg+1)&1][2] = *reinterpret_cast<const float4*>(np + 32);
        ng[(rg+1)&1][3] = *reinterpret_cast<const float4*>(np + 36);
      }
      float4 cl0 = cg[rg&1][0], cl1 = cg[rg&1][1], ch0 = cg[rg&1][2], ch1 = cg[rg&1][3];
      float4 nl0 = ng[rg&1][0], nl1 = ng[rg&1][1], nh0 = ng[rg&1][2], nh1 = ng[rg&1][3];
      bf16x8v afr[4];
      afr[0][0]=(__bf16)cl0.x; afr[0][1]=(__bf16)cl0.y; afr[0][2]=(__bf16)cl0.z; afr[0][3]=(__bf16)cl0.w;
      afr[0][4]=(__bf16)cl1.x; afr[0][5]=(__bf16)cl1.y; afr[0][6]=(__bf16)cl1.z; afr[0][7]=(__bf16)cl1.w;
      afr[1][0]=(__bf16)ch0.x; afr[1][1]=(__bf16)ch0.y; afr[1][2]=(__bf16)ch0.z; afr[1][3]=(__bf16)ch0.w;
      afr[1][4]=(__bf16)ch1.x; afr[1][5]=(__bf16)ch1.y; afr[1][6]=(__bf16)ch1.z; afr[1][7]=(__bf16)ch1.w;
      afr[2][0]=(__bf16)(nl0.x-cl0.x); afr[2][1]=(__bf16)(nl0.y-cl0.y);
      afr[2][2]=(__bf16)(nl0.z-cl0.z); afr[2][3]=(__bf16)(nl0.w-cl0.w);
      afr[2][4]=(__bf16)(nl1.x-cl1.x); afr[2][5]=(__bf16)(nl1.y-cl1.y);
      afr[2][6]=(__bf16)(nl1.z-cl1.z); afr[2][7]=(__bf16)(nl1.w-cl1.w);
      afr[3][0]=(__bf16)(nh0.x-ch0.x); afr[3][1]=(__bf16)(nh0.y-ch0.y);
      afr[3][2]=(__bf16)(nh0.z-ch0.z); afr[3][3]=(__bf16)(nh0.w-ch0.w);
      afr[3][4]=(__bf16)(nh1.x-ch1.x); afr[3][5]=(__bf16)(nh1.y-ch1.y);
      afr[3][6]=(__bf16)(nh1.z-ch1.z); afr[3][7]=(__bf16)(nh1.w-ch1.w);
      f32x4v acc[8] = {};
      #pragma unroll
      for (int kb=0; kb<4; ++kb){
        #pragma unroll
        for (int cf=0; cf<8; ++cf){
          uint4 b4 = *reinterpret_cast<const uint4*>(&Wl[((kb*8+cf)*64 + l)*8]);
          acc[cf] = __builtin_amdgcn_mfma_f32_16x16x32_bf16(afr[kb], __builtin_bit_cast(bf16x8v, b4), acc[cf], 0, 0, 0);
        }
      }
      epilogue(rg, acc);
    }
  }

  // ---- cross-wave stats (red aliases tb; barrier first) ----
  __syncthreads();
  #pragma unroll
  for (int cf=0; cf<8; ++cf){
    float s = ss[cf];
    s += __shfl_xor(s, 16);
    s += __shfl_xor(s, 32);
    float q = sq[cf];
    q += __shfl_xor(q, 16);
    q += __shfl_xor(q, 32);
    if (lg == 0){
      red[w*128 + cf*16 + li]       = s;
      red[512 + w*128 + cf*16 + li] = q;
    }
  }
  __syncthreads();
  {
    int col = t & 127;
    int base = (t >> 7) * 512;
    float s = red[base + col] + red[base + 128 + col] + red[base + 256 + col] + red[base + 384 + col];
    partials[(size_t)blockIdx.x*256 + (t>>7)*128 + col] = s;
  }
}

// ---------------- shortcut GEMM: feats(64) x Wsc^T -> sc f32 ----------------
__global__ __launch_bounds__(256) void sc_gemm(const float* __restrict__ featsT,
                                               const float* __restrict__ W,
                                               float* __restrict__ scout,
                                               float* __restrict__ partials){
  __shared__ __align__(16) unsigned short Wt[64][136];
  __shared__ __align__(16) unsigned short xs[64][72];
  int t = threadIdx.x, tx = t&15, ty = t>>4;
  int rowbase = blockIdx.x * 64;
  for (int it=0; it<32; ++it){
    int flat = it*256 + t;
    int o = flat>>6, c = flat&63;
    Wt[c][o] = bfr(W[flat]);
  }
  for (int it=0; it<16; ++it){
    int flat = it*256 + t;
    int r = flat>>6, c = flat&63;
    xs[r][c] = bfr(featsT[(size_t)(rowbase + r)*64 + c]);
  }
  __syncthreads();
  float acc[4][8] = {};
  for (int c=0;c<64;++c){
    uint4 wv = *reinterpret_cast<const uint4*>(&Wt[c][tx*8]);
    float w[8];
    w[0]=bl(wv.x); w[1]=bh(wv.x); w[2]=bl(wv.y); w[3]=bh(wv.y);
    w[4]=bl(wv.z); w[5]=bh(wv.z); w[6]=bl(wv.w); w[7]=bh(wv.w);
    #pragma unroll
    for (int i=0;i<4;++i){
      float xv = bl((unsigned)xs[ty*4+i][c]);
      #pragma unroll
      for (int j=0;j<8;++j) acc[i][j] = fmaf(xv, w[j], acc[i][j]);
    }
  }
  #pragma unroll
  for (int i=0;i<4;++i)
    #pragma unroll
    for (int j=0;j<8;++j)
      scout[(size_t)(rowbase + ty*4 + i)*128 + tx*8 + j] = acc[i][j];

  __syncthreads();
  float* red = reinterpret_cast<float*>(&xs[0][0]);
  #pragma unroll
  for (int j=0;j<8;++j){
    float s=0.f;
    #pragma unroll
    for (int i=0;i<4;++i) s += acc[i][j];
    red[ty*128 + tx*8 + j] = s;
  }
  __syncthreads();
  if (t<128){
    float s=0.f;
    for (int y2=0;y2<16;++y2) s += red[y2*128 + t];
    partials[(size_t)blockIdx.x*256 + t] = s;
  }
  __syncthreads();
  #pragma unroll
  for (int j=0;j<8;++j){
    float s=0.f;
    #pragma unroll
    for (int i=0;i<4;++i) s += acc[i][j]*acc[i][j];
    red[ty*128 + tx*8 + j] = s;
  }
  __syncthreads();
  if (t<128){
    float s=0.f;
    for (int y2=0;y2<16;++y2) s += red[y2*128 + t];
    partials[(size_t)blockIdx.x*256 + 128 + t] = s;
  }
}

// ---------------- fused BN stats: one block per channel, strided column sums + tree ----------------
// block c: sum = sum_r partials[r][c], sumsq = sum_r partials[r][128+c]; then scale/bias.
__global__ __launch_bounds__(256) void bn_stats(const float* __restrict__ partials,
                                                int rows, float inv_count,
                                                const float* __restrict__ g,
                                                const float* __restrict__ beta,
                                                float* __restrict__ sbout){
  __shared__ float red[512];
  int c = blockIdx.x;      // channel 0..127
  int t = threadIdx.x;
  float s = 0.f, q = 0.f;
  for (int r = t; r < rows; r += 256){
    s += partials[(size_t)r*256 + c];
    q += partials[(size_t)r*256 + 128 + c];
  }
  red[t] = s; red[256 + t] = q;
  __syncthreads();
  #pragma unroll
  for (int off = 128; off > 0; off >>= 1){
    if (t < off){
      red[t]       += red[t + off];
      red[256 + t] += red[256 + t + off];
    }
    __syncthreads();
  }
  if (t == 0){
    float mean = red[0] * inv_count;
    float var  = fmaxf(red[256] * inv_count - mean*mean, 0.f);
    float rstd = 1.0f / sqrtf(var + 1e-5f);
    float sc = g[c] * rstd;
    sbout[c] = sc;
    sbout[128 + c] = beta[c] - mean*sc;
  }
}

// ---------------- final v2: vectorized y2 loads (uint4) ----------------
__global__ __launch_bounds__(256) void final_kernel(const unsigned short* __restrict__ y2,
                                                    const float* __restrict__ sc,
                                                    const float* __restrict__ sb2,
                                                    const float* __restrict__ sbsc,
                                                    float* __restrict__ out){
  __shared__ __align__(16) float obuf[64][130];
  int t = threadIdx.x;
  int b = blockIdx.x >> 4;
  int n0 = (blockIdx.x & 15) * 64;
  int oc = (t & 15) * 8;     // 8 consecutive channels per thread
  int nl0 = t >> 4;          // 16 rows per pass, 4 passes

  float4 s2a = *reinterpret_cast<const float4*>(sb2 + oc);
  float4 s2b = *reinterpret_cast<const float4*>(sb2 + oc + 4);
  float4 c2a = *reinterpret_cast<const float4*>(sb2 + 128 + oc);
  float4 c2b = *reinterpret_cast<const float4*>(sb2 + 128 + oc + 4);
  float4 ssa = *reinterpret_cast<const float4*>(sbsc + oc);
  float4 ssb = *reinterpret_cast<const float4*>(sbsc + oc + 4);
  float4 csa = *reinterpret_cast<const float4*>(sbsc + 128 + oc);
  float4 csb = *reinterpret_cast<const float4*>(sbsc + 128 + oc + 4);

  #pragma unroll
  for (int p=0; p<4; ++p){
    int nl = p*16 + nl0;
    size_t nglob = (size_t)((b<<10) + n0 + nl);
    const unsigned short* yp = y2 + (nglob<<4)*128 + oc;
    float a0=0,a1=0,a2=0,a3=0,a4=0,a5=0,a6=0,a7=0;
    #pragma unroll
    for (int k=0;k<16;++k){
      uint4 v = *reinterpret_cast<const uint4*>(yp + k*128);
      a0 += fmaxf(fmaf(bl(v.x), s2a.x, c2a.x), 0.f);
      a1 += fmaxf(fmaf(bh(v.x), s2a.y, c2a.y), 0.f);
      a2 += fmaxf(fmaf(bl(v.y), s2a.z, c2a.z), 0.f);
      a3 += fmaxf(fmaf(bh(v.y), s2a.w, c2a.w), 0.f);
      a4 += fmaxf(fmaf(bl(v.z), s2b.x, c2b.x), 0.f);
      a5 += fmaxf(fmaf(bh(v.z), s2b.y, c2b.y), 0.f);
      a6 += fmaxf(fmaf(bl(v.w), s2b.z, c2b.z), 0.f);
      a7 += fmaxf(fmaf(bh(v.w), s2b.w, c2b.w), 0.f);
    }
    const float* scp = sc + nglob*128 + oc;
    float4 v0 = *reinterpret_cast<const float4*>(scp);
    float4 v1 = *reinterpret_cast<const float4*>(scp + 4);
    float4 o0, o1;
    o0.x = fmaxf(fmaf(v0.x, ssa.x, csa.x) + a0*(1.f/16.f), 0.f);
    o0.y = fmaxf(fmaf(v0.y, ssa.y, csa.y) + a1*(1.f/16.f), 0.f);
    o0.z = fmaxf(fmaf(v0.z, ssa.z, csa.z) + a2*(1.f/16.f), 0.f);
    o0.w = fmaxf(fmaf(v0.w, ssa.w, csa.w) + a3*(1.f/16.f), 0.f);
    o1.x = fmaxf(fmaf(v1.x, ssb.x, csb.x) + a4*(1.f/16.f), 0.f);
    o1.y = fmaxf(fmaf(v1.y, ssb.y, csb.y) + a5*(1.f/16.f), 0.f);
    o1.z = fmaxf(fmaf(v1.z, ssb.z, csb.z) + a6*(1.f/16.f), 0.f);
    o1.w = fmaxf(fmaf(v1.w, ssb.w, csb.w) + a7*(1.f/16.f), 0.f);
    *reinterpret_cast<float4*>(&obuf[nl][oc])     = o0;
    *reinterpret_cast<float4*>(&obuf[nl][oc + 4]) = o1;
  }
  __syncthreads();
  for (int it=0; it<32; ++it){
    int flat = it*256 + t;
    int oo = flat>>6, nl = flat&63;
    out[((size_t)b<<17) + (oo<<10) + n0 + nl] = obuf[nl][oo];
  }
}

extern "C" void kernel_launch(void* const* d_in, const int* in_sizes, int n_in,
                              void* d_out, int out_size, void* d_ws, size_t ws_size,
                              hipStream_t stream) {
  const float* points   = (const float*)d_in[0];
  const float* features = (const float*)d_in[1];
  const float* W0  = (const float*)d_in[2];
  const float* g0  = (const float*)d_in[3];
  const float* b0  = (const float*)d_in[4];
  const float* W1  = (const float*)d_in[5];
  const float* g1  = (const float*)d_in[6];
  const float* b1  = (const float*)d_in[7];
  const float* W2  = (const float*)d_in[8];
  const float* g2  = (const float*)d_in[9];
  const float* b2  = (const float*)d_in[10];
  const float* Wsc = (const float*)d_in[11];
  const float* gsc = (const float*)d_in[12];
  const float* bsc = (const float*)d_in[13];

  float* out = (float*)d_out;

  if (ws_size < WS_NEED){
    float v = (float)(ws_size >> 20);
    sentinel_kernel<<<(out_size + 255)/256, 256, 0, stream>>>(out, out_size, v);
    return;
  }

  char* ws = (char*)d_ws;
  float*          featsT = (float*)(ws + OFF_FT);
  int*            idx    = (int*)(ws + OFF_IDX);
  unsigned short* y      = (unsigned short*)(ws + OFF_Y);
  float*          scbuf  = (float*)(ws + OFF_SC);
  float*          part   = (float*)(ws + OFF_PART);
  unsigned short* WB     = (unsigned short*)(ws + OFF_WB);
  float*          sb     = (float*)(ws + OFF_SB);

  // fused prologue: transpose (512) | convert_w (24) | knn (1024)
  prep_kernel<<<1560, 256, 0, stream>>>(features, points, W0, W1, W2, featsT, WB, idx);

  // layer 0 (gather + MFMA, W in LDS pre-swizzled, pipelined gather)
  gemm4<0><<<NROW/256, 256, 0, stream>>>(featsT, idx, nullptr, nullptr, WB, y, part);
  bn_stats<<<128, 256, 0, stream>>>(part, 2048, 1.f/524288.f, g0, b0, sb + 0);
  // layer 1 (in-place, 1-ahead y prefetch)
  gemm4<1><<<NROW/256, 256, 0, stream>>>(nullptr, nullptr, y, sb + 0, WB + 16384, y, part);
  bn_stats<<<128, 256, 0, stream>>>(part, 2048, 1.f/524288.f, g1, b1, sb + 256);
  // layer 2 (in-place, 1-ahead y prefetch)
  gemm4<1><<<NROW/256, 256, 0, stream>>>(nullptr, nullptr, y, sb + 256, WB + 32768, y, part);
  bn_stats<<<128, 256, 0, stream>>>(part, 2048, 1.f/524288.f, g2, b2, sb + 512);
  // shortcut
  sc_gemm<<<NROWSC/64, 256, 0, stream>>>(featsT, Wsc, scbuf, part);
  bn_stats<<<128, 256, 0, stream>>>(part, 512, 1.f/32768.f, gsc, bsc, sb + 768);
  // fuse + transpose
  final_kernel<<<512, 256, 0, stream>>>(y, scbuf, sb + 512, sb + 768, out);
}

// Round 20
// 290.581 us; speedup vs baseline: 2.9933x; 1.0509x over previous
//
#include <hip/hip_runtime.h>

// EdgeConvBlock: B=32, N=1024, D=3, CIN=64, K=16, COUT=128x3
// Round 20: fold sc_gemm into prep_kernel (4th block range, reads raw features,
// partials -> part2) and merge its bn_stats with layer-0's (bn_stats2, 256 blocks).
// 10 dispatches -> 8. Hot kernels identical to r19 (305.4us).

#define BB 32
#define NN 1024
#define CINC 64
#define KK 16
#define CO 128
#define NROW (BB*NN*KK)   // 524288
#define NROWSC (BB*NN)    // 32768

// ---- ws layout (bytes) ----
static const size_t OFF_FT   = 0;            // featsT f32 [B][N][64]       8,388,608
static const size_t OFF_IDX  = 8388608;      // idx int  [B][N][16]         2,097,152
static const size_t OFF_Y    = 10485760;     // y  bf16  [NROW][128]      134,217,728
static const size_t OFF_SC   = 144703488;    // sc f32   [NROWSC][128]     16,777,216
static const size_t OFF_PART = 161480704;    // layer partials f32 [2048][256]  2,097,152
static const size_t OFF_PART2= 163577856;    // sc partials f32 [512][256]      524,288
static const size_t OFF_WB   = 165675008;    // swizzled bf16 W [3][16384]     98,304
static const size_t OFF_SB   = 169934848;    // scale/bias f32 [4][256]         4,096
static const size_t WS_NEED  = 169938944;

typedef __bf16 bf16x8v __attribute__((ext_vector_type(8)));
typedef float  f32x4v  __attribute__((ext_vector_type(4)));

__device__ __forceinline__ float bl(unsigned u){ return __uint_as_float(u<<16); }
__device__ __forceinline__ float bh(unsigned u){ return __uint_as_float(u & 0xffff0000u); }
__device__ __forceinline__ unsigned short bfr(float x){
  unsigned u = __float_as_uint(x);
  u += 0x7fffu + ((u>>16)&1u);
  return (unsigned short)(u>>16);
}
__device__ __forceinline__ unsigned short b16(float x){
  return __builtin_bit_cast(unsigned short, (__bf16)x);   // HW RNE convert
}

// ---------------- diagnostic sentinel ----------------
__global__ __launch_bounds__(256) void sentinel_kernel(float* __restrict__ out, int n, float v){
  int i = blockIdx.x*256 + threadIdx.x;
  if (i < n) out[i] = v;
}

// ---------------- fused prologue: transpose(512) | convert_w(24) | knn(1024) | sc_gemm(512) ----------------
__global__ __launch_bounds__(256) void prep_kernel(const float* __restrict__ f,
                                                   const float* __restrict__ pts,
                                                   const float* __restrict__ W0,
                                                   const float* __restrict__ W1,
                                                   const float* __restrict__ W2,
                                                   const float* __restrict__ Wsc,
                                                   float* __restrict__ ft,
                                                   unsigned short* __restrict__ WB,
                                                   int* __restrict__ idxout,
                                                   float* __restrict__ scout,
                                                   float* __restrict__ part2){
  __shared__ __align__(16) char smem[34816];
  int t = threadIdx.x;
  int bid = blockIdx.x;

  if (bid < 512){
    // ---- transpose features (b,c,n) -> (b,n,c) ----
    float (*tile)[65] = (float(*)[65])smem;     // 16.6KB of 34.8KB
    int b = bid >> 4, n0 = (bid & 15) * 64;
    for (int it=0; it<16; ++it){
      int flat = it*256 + t;
      int c = flat>>6, nl = flat&63;
      tile[c][nl] = f[(b*64 + c)*1024 + n0 + nl];
    }
    __syncthreads();
    for (int it=0; it<16; ++it){
      int flat = it*256 + t;
      int nl = flat>>6, c = flat&63;
      ft[((b<<10) + n0 + nl)*64 + c] = tile[c][nl];
    }
    return;
  }

  if (bid < 536){
    // ---- weight pre-swizzle: WB[lay][(kb*8+cf)*64+l][j] = W[cf*16+(l&15)][kb*32+(l>>4)*8+j] ----
    int tid = (bid - 512)*256 + t;               // 0..6143
    int lay = tid >> 11, rem = tid & 2047;
    int fidx = rem >> 6, l = rem & 63;
    int kb = fidx >> 3, cf = fidx & 7;
    int li = l & 15, lg = l >> 4;
    const float* Ws = lay==0 ? W0 : (lay==1 ? W1 : W2);
    int o = cf*16 + li;
    unsigned short p[8];
    #pragma unroll
    for (int j=0;j<8;++j) p[j] = bfr(Ws[o*128 + kb*32 + lg*8 + j]);
    uint4 o4;
    o4.x = (unsigned)p[0] | ((unsigned)p[1]<<16);
    o4.y = (unsigned)p[2] | ((unsigned)p[3]<<16);
    o4.z = (unsigned)p[4] | ((unsigned)p[5]<<16);
    o4.w = (unsigned)p[6] | ((unsigned)p[7]<<16);
    *reinterpret_cast<uint4*>(WB + (size_t)lay*16384 + (size_t)rem*8) = o4;
    return;
  }

  if (bid < 1560){
    // ---- KNN v4: packed-key cascade, 32 queries x 8 chunks of 128 ----
    int kbid = bid - 536;
    int b = kbid >> 5, g = kbid & 31;
    float4* p4 = (float4*)smem;                          // [1024] during scan
    unsigned long long (*mk)[32][17] =
        (unsigned long long(*)[32][17])smem;             // [8][32][17] keys after scan

    for (int i=t; i<1024; i+=256){
      float a = pts[(b*3+0)*1024+i];
      float c = pts[(b*3+1)*1024+i];
      float d = pts[(b*3+2)*1024+i];
      float xx = __fadd_rn(__fadd_rn(__fmul_rn(a,a), __fmul_rn(c,c)), __fmul_rn(d,d));
      p4[i] = make_float4(a, c, d, xx);
    }
    __syncthreads();

    int q = t & 31, c = t >> 5;       // query-in-block, chunk
    int n = g*32 + q;
    float4 qp = p4[n];
    float qx=qp.x, qy=qp.y, qz=qp.z, qxx=qp.w;
    double vals[16];
    #pragma unroll
    for (int j=0;j<16;++j) vals[j] = 0.0;

    int m0 = c*128;
    for (int i0=0; i0<128; i0+=4){
      float4 cand[4];
      #pragma unroll
      for (int u=0;u<4;++u) cand[u] = p4[m0 + i0 + u];
      #pragma unroll
      for (int u=0;u<4;++u){
        int m = m0 + i0 + u;
        float inner = __fadd_rn(__fadd_rn(__fmul_rn(qx,cand[u].x), __fmul_rn(qy,cand[u].y)), __fmul_rn(qz,cand[u].z));
        float pd = __fsub_rn(__fsub_rn(__fmul_rn(2.0f, inner), qxx), cand[u].w);
        unsigned uv = __float_as_uint(pd);
        unsigned fk = uv ^ (0x80000000u | (unsigned)((int)uv >> 31));  // monotone f32->u32
        unsigned lo = (fk << 20) | (unsigned)(1023 - m);
        unsigned hi = 0x40000000u | (fk >> 12);
        hi = (m == n) ? 0u : hi;                                       // self -> tiny key
        double key = __builtin_bit_cast(double, ((unsigned long long)hi << 32) | lo);
        #pragma unroll
        for (int j=0;j<16;++j){
          double mx = fmax(vals[j], key);
          key = fmin(vals[j], key);
          vals[j] = mx;
        }
      }
    }
    __syncthreads();                    // scans done; points dead -> key lists live
    #pragma unroll
    for (int j=0;j<16;++j) mk[c][q][j] = __builtin_bit_cast(unsigned long long, vals[j]);
    mk[c][q][16] = 0ull;                // sentinel
    __syncthreads();

    if (t < 32){
      int qq = t;
      int p0=0,p1=0,p2=0,p3=0,p4i=0,p5=0,p6=0,p7=0;
      unsigned long long v0=mk[0][qq][0], v1=mk[1][qq][0], v2=mk[2][qq][0], v3=mk[3][qq][0];
      unsigned long long v4=mk[4][qq][0], v5=mk[5][qq][0], v6=mk[6][qq][0], v7=mk[7][qq][0];
      int* dst = idxout + ((size_t)((b<<10) + g*32 + qq))*16;
      #pragma unroll
      for (int j=0;j<16;++j){
        unsigned long long best = v0; int bc = 0;
        if (v1 > best){ best = v1; bc = 1; }
        if (v2 > best){ best = v2; bc = 2; }
        if (v3 > best){ best = v3; bc = 3; }
        if (v4 > best){ best = v4; bc = 4; }
        if (v5 > best){ best = v5; bc = 5; }
        if (v6 > best){ best = v6; bc = 6; }
        if (v7 > best){ best = v7; bc = 7; }
        dst[j] = 1023 - (int)(best & 1023ull);
        if      (bc==0){ ++p0; v0 = mk[0][qq][p0]; }
        else if (bc==1){ ++p1; v1 = mk[1][qq][p1]; }
        else if (bc==2){ ++p2; v2 = mk[2][qq][p2]; }
        else if (bc==3){ ++p3; v3 = mk[3][qq][p3]; }
        else if (bc==4){ ++p4i; v4 = mk[4][qq][p4i]; }
        else if (bc==5){ ++p5; v5 = mk[5][qq][p5]; }
        else if (bc==6){ ++p6; v6 = mk[6][qq][p6]; }
        else           { ++p7; v7 = mk[7][qq][p7]; }
      }
    }
    return;
  }

  // ---- shortcut GEMM (from raw features, transposed load): 64 rows x 128 out ----
  {
    int scb = bid - 1560;                 // 0..511
    int rowbase = scb * 64;
    int b = rowbase >> 10, n0 = rowbase & 1023;
    unsigned short (*Wt)[136] = (unsigned short(*)[136])smem;            // 17,408 B
    unsigned short (*xs)[72]  = (unsigned short(*)[72])(smem + 17408);   //  9,216 B
    float* red = (float*)(smem + 17408);                                 // alias xs (post-barrier)
    int tx = t & 15, ty = t >> 4;

    for (int it=0; it<32; ++it){
      int flat = it*256 + t;
      int o = flat>>6, c = flat&63;
      Wt[c][o] = bfr(Wsc[flat]);
    }
    for (int it=0; it<16; ++it){
      int flat = it*256 + t;
      int c = flat>>6, nl = flat&63;
      xs[nl][c] = bfr(f[(b*64 + c)*1024 + n0 + nl]);   // coalesced read, LDS transpose scatter
    }
    __syncthreads();
    float acc[4][8] = {};
    for (int c=0;c<64;++c){
      uint4 wv = *reinterpret_cast<const uint4*>(&Wt[c][tx*8]);
      float w[8];
      w[0]=bl(wv.x); w[1]=bh(wv.x); w[2]=bl(wv.y); w[3]=bh(wv.y);
      w[4]=bl(wv.z); w[5]=bh(wv.z); w[6]=bl(wv.w); w[7]=bh(wv.w);
      #pragma unroll
      for (int i=0;i<4;++i){
        float xv = bl((unsigned)xs[ty*4+i][c]);
        #pragma unroll
        for (int j=0;j<8;++j) acc[i][j] = fmaf(xv, w[j], acc[i][j]);
      }
    }
    #pragma unroll
    for (int i=0;i<4;++i)
      #pragma unroll
      for (int j=0;j<8;++j)
        scout[(size_t)(rowbase + ty*4 + i)*128 + tx*8 + j] = acc[i][j];

    __syncthreads();
    #pragma unroll
    for (int j=0;j<8;++j){
      float s=0.f;
      #pragma unroll
      for (int i=0;i<4;++i) s += acc[i][j];
      red[ty*128 + tx*8 + j] = s;
    }
    __syncthreads();
    if (t<128){
      float s=0.f;
      for (int y2=0;y2<16;++y2) s += red[y2*128 + t];
      part2[(size_t)scb*256 + t] = s;
    }
    __syncthreads();
    #pragma unroll
    for (int j=0;j<8;++j){
      float s=0.f;
      #pragma unroll
      for (int i=0;i<4;++i) s += acc[i][j]*acc[i][j];
      red[ty*128 + tx*8 + j] = s;
    }
    __syncthreads();
    if (t<128){
      float s=0.f;
      for (int y2=0;y2<16;++y2) s += red[y2*128 + t];
      part2[(size_t)scb*256 + 128 + t] = s;
    }
  }
}

// ---------------- GEMM v4 (verified best): 256x128 per block, K=128, 1-ahead prefetch ----------------
// MODE 0: x = (center || nbr-center); MODE 1: x = relu(yin*s+b), in-place safe.
template<int MODE>
__global__ __launch_bounds__(256, 2) void gemm4(const float* __restrict__ featsT,
                                                const int* __restrict__ knnidx,
                                                const unsigned short* yin,
                                                const float* __restrict__ sb,
                                                const unsigned short* __restrict__ Wswz,
                                                unsigned short* yout,
                                                float* __restrict__ partials){
  __shared__ __align__(16) unsigned short Wl[16384];       // 32KB swizzled W
  __shared__ __align__(16) unsigned short tb[4][16][132];  // 16.9KB per-wave transpose
  float* red = (float*)&tb[0][0][0];                       // 4KB alias (used after barrier)

  int t = threadIdx.x;
  int w = t >> 6, l = t & 63;
  int li = l & 15, lg = l >> 4;

  // stage swizzled W: linear 32KB copy
  #pragma unroll
  for (int it=0; it<8; ++it){
    int v = it*256 + t;
    *reinterpret_cast<uint4*>(&Wl[v*8]) =
      *reinterpret_cast<const uint4*>(Wswz + (size_t)v*8);
  }
  __syncthreads();

  float ss[8] = {0.f,0.f,0.f,0.f,0.f,0.f,0.f,0.f};
  float sq[8] = {0.f,0.f,0.f,0.f,0.f,0.f,0.f,0.f};

  // -------- epilogue (shared by both modes) --------
  auto epilogue = [&](int rg, f32x4v (&acc)[8]){
    size_t rbase = (size_t)blockIdx.x*256 + w*64 + rg*16;
    #pragma unroll
    for (int cf=0; cf<8; ++cf){
      ss[cf] += acc[cf][0]+acc[cf][1]+acc[cf][2]+acc[cf][3];
      sq[cf] += acc[cf][0]*acc[cf][0]+acc[cf][1]*acc[cf][1]+acc[cf][2]*acc[cf][2]+acc[cf][3]*acc[cf][3];
    }
    #pragma unroll
    for (int cf=0; cf<8; ++cf){
      tb[w][lg*4 + 0][cf*16 + li] = b16(acc[cf][0]);
      tb[w][lg*4 + 1][cf*16 + li] = b16(acc[cf][1]);
      tb[w][lg*4 + 2][cf*16 + li] = b16(acc[cf][2]);
      tb[w][lg*4 + 3][cf*16 + li] = b16(acc[cf][3]);
    }
    __builtin_amdgcn_wave_barrier();   // scatter writes before cross-lane reads
    {
      int row4 = l >> 4, ch = l & 15;
      #pragma unroll
      for (int s2=0; s2<4; ++s2){
        const unsigned short* src = &tb[w][s2*4 + row4][ch*8];
        unsigned short* dst = yout + (rbase + s2*4 + row4)*128 + ch*8;
        *reinterpret_cast<uint4*>(dst) = *reinterpret_cast<const uint4*>(src);
      }
    }
    __builtin_amdgcn_wave_barrier();   // reads done before next rg's scatter
  };

  if constexpr (MODE == 1){
    const unsigned short* ybase = yin + ((size_t)blockIdx.x*256 + w*64 + li)*128 + lg*8;
    uint4 yb[2][4];
    #pragma unroll
    for (int kb=0; kb<4; ++kb)
      yb[0][kb] = *reinterpret_cast<const uint4*>(ybase + kb*32);
    #pragma unroll
    for (int rg=0; rg<4; ++rg){
      if (rg < 3){   // 1-ahead prefetch (issued before any compute/barrier of this rg)
        #pragma unroll
        for (int kb=0; kb<4; ++kb)
          yb[(rg+1)&1][kb] = *reinterpret_cast<const uint4*>(ybase + (size_t)(rg+1)*2048 + kb*32);
      }
      f32x4v acc[8] = {};
      #pragma unroll
      for (int kb=0; kb<4; ++kb){
        int c0 = kb*32 + lg*8;
        uint4 yv = yb[rg&1][kb];
        float4 s0 = *reinterpret_cast<const float4*>(sb + c0);
        float4 s1 = *reinterpret_cast<const float4*>(sb + c0 + 4);
        float4 b0 = *reinterpret_cast<const float4*>(sb + 128 + c0);
        float4 b1 = *reinterpret_cast<const float4*>(sb + 128 + c0 + 4);
        bf16x8v av;
        av[0] = (__bf16)fmaxf(fmaf(bl(yv.x), s0.x, b0.x), 0.f);
        av[1] = (__bf16)fmaxf(fmaf(bh(yv.x), s0.y, b0.y), 0.f);
        av[2] = (__bf16)fmaxf(fmaf(bl(yv.y), s0.z, b0.z), 0.f);
        av[3] = (__bf16)fmaxf(fmaf(bh(yv.y), s0.w, b0.w), 0.f);
        av[4] = (__bf16)fmaxf(fmaf(bl(yv.z), s1.x, b1.x), 0.f);
        av[5] = (__bf16)fmaxf(fmaf(bh(yv.z), s1.y, b1.y), 0.f);
        av[6] = (__bf16)fmaxf(fmaf(bl(yv.w), s1.z, b1.z), 0.f);
        av[7] = (__bf16)fmaxf(fmaf(bh(yv.w), s1.w, b1.w), 0.f);
        #pragma unroll
        for (int cf=0; cf<8; ++cf){
          uint4 b4 = *reinterpret_cast<const uint4*>(&Wl[((kb*8+cf)*64 + l)*8]);
          acc[cf] = __builtin_amdgcn_mfma_f32_16x16x32_bf16(av, __builtin_bit_cast(bf16x8v, b4), acc[cf], 0, 0, 0);
        }
      }
      epilogue(rg, acc);
    }
  } else {
    int b = blockIdx.x >> 6;                     // 64 blocks per batch
    int nbase = (blockIdx.x & 63)*16 + w*4;      // point n for rg = nbase + rg
    const float* fb = featsT + (((size_t)b)<<10)*64;
    int nbr[4];
    #pragma unroll
    for (int rg=0; rg<4; ++rg)
      nbr[rg] = knnidx[((size_t)((b<<10) + nbase + rg))*16 + li];
    float4 cg[2][4], ng[2][4];
    {
      const float* cp = fb + (size_t)nbase*64 + lg*8;
      const float* np = fb + (size_t)nbr[0]*64 + lg*8;
      cg[0][0] = *reinterpret_cast<const float4*>(cp);
      cg[0][1] = *reinterpret_cast<const float4*>(cp + 4);
      cg[0][2] = *reinterpret_cast<const float4*>(cp + 32);
      cg[0][3] = *reinterpret_cast<const float4*>(cp + 36);
      ng[0][0] = *reinterpret_cast<const float4*>(np);
      ng[0][1] = *reinterpret_cast<const float4*>(np + 4);
      ng[0][2] = *reinterpret_cast<const float4*>(np + 32);
      ng[0][3] = *reinterpret_cast<const float4*>(np + 36);
    }
    #pragma unroll
    for (int rg=0; rg<4; ++rg){
      if (rg < 3){   // prefetch next rg's gather
        const float* cp = fb + (size_t)(nbase + rg + 1)*64 + lg*8;
        const float* np = fb + (size_t)nbr[rg+1]*64 + lg*8;
        cg[(rg+1)&1][0] = *reinterpret_cast<const float4*>(cp);
        cg[(rg+1)&1][1] = *reinterpret_cast<const float4*>(cp + 4);
        cg[(rg+1)&1][2] = *reinterpret_cast<const float4*>(cp + 32);
        cg[(rg+1)&1][3] = *reinterpret_cast<const float4*>(cp + 36);
        ng[(rg+1)&1][0] = *reinterpret_cast<const float4*>(np);
        ng[(rg+1)&1][1] = *reinterpret_cast<const float4*>(np + 4);
        ng[(rg+1)&1][2] = *reinterpret_cast<const float4*>(np + 32);
        ng[(rg+1)&1][3] = *reinterpret_cast<const float4*>(np + 36);
      }
      float4 cl0 = cg[rg&1][0], cl1 = cg[rg&1][1], ch0 = cg[rg&1][2], ch1 = cg[rg&1][3];
      float4 nl0 = ng[rg&1][0], nl1 = ng[rg&1][1], nh0 = ng[rg&1][2], nh1 = ng[rg&1][3];
      bf16x8v afr[4];
      afr[0][0]=(__bf16)cl0.x; afr[0][1]=(__bf16)cl0.y; afr[0][2]=(__bf16)cl0.z; afr[0][3]=(__bf16)cl0.w;
      afr[0][4]=(__bf16)cl1.x; afr[0][5]=(__bf16)cl1.y; afr[0][6]=(__bf16)cl1.z; afr[0][7]=(__bf16)cl1.w;
      afr[1][0]=(__bf16)ch0.x; afr[1][1]=(__bf16)ch0.y; afr[1][2]=(__bf16)ch0.z; afr[1][3]=(__bf16)ch0.w;
      afr[1][4]=(__bf16)ch1.x; afr[1][5]=(__bf16)ch1.y; afr[1][6]=(__bf16)ch1.z; afr[1][7]=(__bf16)ch1.w;
      afr[2][0]=(__bf16)(nl0.x-cl0.x); afr[2][1]=(__bf16)(nl0.y-cl0.y);
      afr[2][2]=(__bf16)(nl0.z-cl0.z); afr[2][3]=(__bf16)(nl0.w-cl0.w);
      afr[2][4]=(__bf16)(nl1.x-cl1.x); afr[2][5]=(__bf16)(nl1.y-cl1.y);
      afr[2][6]=(__bf16)(nl1.z-cl1.z); afr[2][7]=(__bf16)(nl1.w-cl1.w);
      afr[3][0]=(__bf16)(nh0.x-ch0.x); afr[3][1]=(__bf16)(nh0.y-ch0.y);
      afr[3][2]=(__bf16)(nh0.z-ch0.z); afr[3][3]=(__bf16)(nh0.w-ch0.w);
      afr[3][4]=(__bf16)(nh1.x-ch1.x); afr[3][5]=(__bf16)(nh1.y-ch1.y);
      afr[3][6]=(__bf16)(nh1.z-ch1.z); afr[3][7]=(__bf16)(nh1.w-ch1.w);
      f32x4v acc[8] = {};
      #pragma unroll
      for (int kb=0; kb<4; ++kb){
        #pragma unroll
        for (int cf=0; cf<8; ++cf){
          uint4 b4 = *reinterpret_cast<const uint4*>(&Wl[((kb*8+cf)*64 + l)*8]);
          acc[cf] = __builtin_amdgcn_mfma_f32_16x16x32_bf16(afr[kb], __builtin_bit_cast(bf16x8v, b4), acc[cf], 0, 0, 0);
        }
      }
      epilogue(rg, acc);
    }
  }

  // ---- cross-wave stats (red aliases tb; barrier first) ----
  __syncthreads();
  #pragma unroll
  for (int cf=0; cf<8; ++cf){
    float s = ss[cf];
    s += __shfl_xor(s, 16);
    s += __shfl_xor(s, 32);
    float q = sq[cf];
    q += __shfl_xor(q, 16);
    q += __shfl_xor(q, 32);
    if (lg == 0){
      red[w*128 + cf*16 + li]       = s;
      red[512 + w*128 + cf*16 + li] = q;
    }
  }
  __syncthreads();
  {
    int col = t & 127;
    int base = (t >> 7) * 512;
    float s = red[base + col] + red[base + 128 + col] + red[base + 256 + col] + red[base + 384 + col];
    partials[(size_t)blockIdx.x*256 + (t>>7)*128 + col] = s;
  }
}

// ---------------- BN stats: one block per channel, strided column sums + tree ----------------
__global__ __launch_bounds__(256) void bn_stats(const float* __restrict__ partials,
                                                int rows, float inv_count,
                                                const float* __restrict__ g,
                                                const float* __restrict__ beta,
                                                float* __restrict__ sbout){
  __shared__ float red[512];
  int c = blockIdx.x;      // channel 0..127
  int t = threadIdx.x;
  float s = 0.f, q = 0.f;
  for (int r = t; r < rows; r += 256){
    s += partials[(size_t)r*256 + c];
    q += partials[(size_t)r*256 + 128 + c];
  }
  red[t] = s; red[256 + t] = q;
  __syncthreads();
  #pragma unroll
  for (int off = 128; off > 0; off >>= 1){
    if (t < off){
      red[t]       += red[t + off];
      red[256 + t] += red[256 + t + off];
    }
    __syncthreads();
  }
  if (t == 0){
    float mean = red[0] * inv_count;
    float var  = fmaxf(red[256] * inv_count - mean*mean, 0.f);
    float rstd = 1.0f / sqrtf(var + 1e-5f);
    float sc = g[c] * rstd;
    sbout[c] = sc;
    sbout[128 + c] = beta[c] - mean*sc;
  }
}

// ---------------- dual BN stats: blocks 0-127 layer A, 128-255 shortcut B ----------------
__global__ __launch_bounds__(256) void bn_stats2(const float* __restrict__ partA,
                                                 const float* __restrict__ partB,
                                                 const float* __restrict__ gA,
                                                 const float* __restrict__ bA,
                                                 const float* __restrict__ gB,
                                                 const float* __restrict__ bB,
                                                 float* __restrict__ outA,
                                                 float* __restrict__ outB){
  __shared__ float red[512];
  int blk = blockIdx.x;
  int t = threadIdx.x;
  const float* part; int rows; float inv; const float* g; const float* be; float* o; int c;
  if (blk < 128){ part = partA; rows = 2048; inv = 1.f/524288.f; g = gA; be = bA; o = outA; c = blk; }
  else          { part = partB; rows = 512;  inv = 1.f/32768.f;  g = gB; be = bB; o = outB; c = blk - 128; }
  float s = 0.f, q = 0.f;
  for (int r = t; r < rows; r += 256){
    s += part[(size_t)r*256 + c];
    q += part[(size_t)r*256 + 128 + c];
  }
  red[t] = s; red[256 + t] = q;
  __syncthreads();
  #pragma unroll
  for (int off = 128; off > 0; off >>= 1){
    if (t < off){
      red[t]       += red[t + off];
      red[256 + t] += red[256 + t + off];
    }
    __syncthreads();
  }
  if (t == 0){
    float mean = red[0] * inv;
    float var  = fmaxf(red[256] * inv - mean*mean, 0.f);
    float rstd = 1.0f / sqrtf(var + 1e-5f);
    float sc = g[c] * rstd;
    o[c] = sc;
    o[128 + c] = be[c] - mean*sc;
  }
}

// ---------------- final v2: vectorized y2 loads (uint4) ----------------
__global__ __launch_bounds__(256) void final_kernel(const unsigned short* __restrict__ y2,
                                                    const float* __restrict__ sc,
                                                    const float* __restrict__ sb2,
                                                    const float* __restrict__ sbsc,
                                                    float* __restrict__ out){
  __shared__ __align__(16) float obuf[64][130];
  int t = threadIdx.x;
  int b = blockIdx.x >> 4;
  int n0 = (blockIdx.x & 15) * 64;
  int oc = (t & 15) * 8;     // 8 consecutive channels per thread
  int nl0 = t >> 4;          // 16 rows per pass, 4 passes

  float4 s2a = *reinterpret_cast<const float4*>(sb2 + oc);
  float4 s2b = *reinterpret_cast<const float4*>(sb2 + oc + 4);
  float4 c2a = *reinterpret_cast<const float4*>(sb2 + 128 + oc);
  float4 c2b = *reinterpret_cast<const float4*>(sb2 + 128 + oc + 4);
  float4 ssa = *reinterpret_cast<const float4*>(sbsc + oc);
  float4 ssb = *reinterpret_cast<const float4*>(sbsc + oc + 4);
  float4 csa = *reinterpret_cast<const float4*>(sbsc + 128 + oc);
  float4 csb = *reinterpret_cast<const float4*>(sbsc + 128 + oc + 4);

  #pragma unroll
  for (int p=0; p<4; ++p){
    int nl = p*16 + nl0;
    size_t nglob = (size_t)((b<<10) + n0 + nl);
    const unsigned short* yp = y2 + (nglob<<4)*128 + oc;
    float a0=0,a1=0,a2=0,a3=0,a4=0,a5=0,a6=0,a7=0;
    #pragma unroll
    for (int k=0;k<16;++k){
      uint4 v = *reinterpret_cast<const uint4*>(yp + k*128);
      a0 += fmaxf(fmaf(bl(v.x), s2a.x, c2a.x), 0.f);
      a1 += fmaxf(fmaf(bh(v.x), s2a.y, c2a.y), 0.f);
      a2 += fmaxf(fmaf(bl(v.y), s2a.z, c2a.z), 0.f);
      a3 += fmaxf(fmaf(bh(v.y), s2a.w, c2a.w), 0.f);
      a4 += fmaxf(fmaf(bl(v.z), s2b.x, c2b.x), 0.f);
      a5 += fmaxf(fmaf(bh(v.z), s2b.y, c2b.y), 0.f);
      a6 += fmaxf(fmaf(bl(v.w), s2b.z, c2b.z), 0.f);
      a7 += fmaxf(fmaf(bh(v.w), s2b.w, c2b.w), 0.f);
    }
    const float* scp = sc + nglob*128 + oc;
    float4 v0 = *reinterpret_cast<const float4*>(scp);
    float4 v1 = *reinterpret_cast<const float4*>(scp + 4);
    float4 o0, o1;
    o0.x = fmaxf(fmaf(v0.x, ssa.x, csa.x) + a0*(1.f/16.f), 0.f);
    o0.y = fmaxf(fmaf(v0.y, ssa.y, csa.y) + a1*(1.f/16.f), 0.f);
    o0.z = fmaxf(fmaf(v0.z, ssa.z, csa.z) + a2*(1.f/16.f), 0.f);
    o0.w = fmaxf(fmaf(v0.w, ssa.w, csa.w) + a3*(1.f/16.f), 0.f);
    o1.x = fmaxf(fmaf(v1.x, ssb.x, csb.x) + a4*(1.f/16.f), 0.f);
    o1.y = fmaxf(fmaf(v1.y, ssb.y, csb.y) + a5*(1.f/16.f), 0.f);
    o1.z = fmaxf(fmaf(v1.z, ssb.z, csb.z) + a6*(1.f/16.f), 0.f);
    o1.w = fmaxf(fmaf(v1.w, ssb.w, csb.w) + a7*(1.f/16.f), 0.f);
    *reinterpret_cast<float4*>(&obuf[nl][oc])     = o0;
    *reinterpret_cast<float4*>(&obuf[nl][oc + 4]) = o1;
  }
  __syncthreads();
  for (int it=0; it<32; ++it){
    int flat = it*256 + t;
    int oo = flat>>6, nl = flat&63;
    out[((size_t)b<<17) + (oo<<10) + n0 + nl] = obuf[nl][oo];
  }
}

extern "C" void kernel_launch(void* const* d_in, const int* in_sizes, int n_in,
                              void* d_out, int out_size, void* d_ws, size_t ws_size,
                              hipStream_t stream) {
  const float* points   = (const float*)d_in[0];
  const float* features = (const float*)d_in[1];
  const float* W0  = (const float*)d_in[2];
  const float* g0  = (const float*)d_in[3];
  const float* b0  = (const float*)d_in[4];
  const float* W1  = (const float*)d_in[5];
  const float* g1  = (const float*)d_in[6];
  const float* b1  = (const float*)d_in[7];
  const float* W2  = (const float*)d_in[8];
  const float* g2  = (const float*)d_in[9];
  const float* b2  = (const float*)d_in[10];
  const float* Wsc = (const float*)d_in[11];
  const float* gsc = (const float*)d_in[12];
  const float* bsc = (const float*)d_in[13];

  float* out = (float*)d_out;

  if (ws_size < WS_NEED){
    float v = (float)(ws_size >> 20);
    sentinel_kernel<<<(out_size + 255)/256, 256, 0, stream>>>(out, out_size, v);
    return;
  }

  char* ws = (char*)d_ws;
  float*          featsT = (float*)(ws + OFF_FT);
  int*            idx    = (int*)(ws + OFF_IDX);
  unsigned short* y      = (unsigned short*)(ws + OFF_Y);
  float*          scbuf  = (float*)(ws + OFF_SC);
  float*          part   = (float*)(ws + OFF_PART);
  float*          part2  = (float*)(ws + OFF_PART2);
  unsigned short* WB     = (unsigned short*)(ws + OFF_WB);
  float*          sb     = (float*)(ws + OFF_SB);

  // fused prologue: transpose(512) | convert_w(24) | knn(1024) | sc_gemm(512)
  prep_kernel<<<2072, 256, 0, stream>>>(features, points, W0, W1, W2, Wsc,
                                        featsT, WB, idx, scbuf, part2);

  // layer 0 (gather + MFMA), then dual stats (layer 0 + shortcut)
  gemm4<0><<<NROW/256, 256, 0, stream>>>(featsT, idx, nullptr, nullptr, WB, y, part);
  bn_stats2<<<256, 256, 0, stream>>>(part, part2, g0, b0, gsc, bsc, sb + 0, sb + 768);
  // layer 1 (in-place, 1-ahead y prefetch)
  gemm4<1><<<NROW/256, 256, 0, stream>>>(nullptr, nullptr, y, sb + 0, WB + 16384, y, part);
  bn_stats<<<128, 256, 0, stream>>>(part, 2048, 1.f/524288.f, g1, b1, sb + 256);
  // layer 2 (in-place, 1-ahead y prefetch)
  gemm4<1><<<NROW/256, 256, 0, stream>>>(nullptr, nullptr, y, sb + 256, WB + 32768, y, part);
  bn_stats<<<128, 256, 0, stream>>>(part, 2048, 1.f/524288.f, g2, b2, sb + 512);
  // fuse + transpose
  final_kernel<<<512, 256, 0, stream>>>(y, scbuf, sb + 512, sb + 768, out);
}